// Round 6
// baseline (187.628 us; speedup 1.0000x reference)
//
#include <hip/hip_runtime.h>
#include <cstddef>
#include <cstdint>

#define HWT   3136        // 56*56
#define WIMG  56
#define CCH   256
#define NH    8
#define QKV_ELEMS (16 * HWT * 32)   // per-tensor q/k/v elements
#define SCALE 0.17677669529663687f  // 32^-0.5

typedef __attribute__((ext_vector_type(8))) short short8;
typedef __attribute__((ext_vector_type(4))) short short4v;
typedef __attribute__((ext_vector_type(4))) float f32x4;
typedef _Float16 half2v __attribute__((ext_vector_type(2)));
typedef _Float16 half4v __attribute__((ext_vector_type(4)));

#if defined(__has_builtin)
#if __has_builtin(__builtin_amdgcn_fdot2)
#define HAVE_FDOT2 1
#endif
#endif
#ifndef HAVE_FDOT2
#define HAVE_FDOT2 0
#endif

__device__ __forceinline__ ushort f2bf(float f) {
  union { float f; uint32_t u; } v; v.f = f;
  uint32_t u = v.u;
  u += 0x7fffu + ((u >> 16) & 1u);   // round-to-nearest-even
  return (ushort)(u >> 16);
}

// ---------------------------------------------------------------------------
// prep: z<2 -> transpose x (b,c,hw) f32 -> xt (b,hw,c) bf16 (32x32 LDS tile)
//       z==2 -> convert qkv_w / proj_w to bf16
// ---------------------------------------------------------------------------
__global__ __launch_bounds__(256) void prep_k(
    const float* __restrict__ x, const float* __restrict__ qkv_w,
    const float* __restrict__ proj_w, ushort* __restrict__ xt,
    ushort* __restrict__ wq, ushort* __restrict__ wp) {
  if (blockIdx.z == 2) {
    int base = ((blockIdx.y * 98 + blockIdx.x) * 256 + threadIdx.x) * 2;
#pragma unroll
    for (int e = base; e < base + 2; ++e) {
      if (e < 768 * 256) wq[e] = f2bf(qkv_w[e]);
      else if (e < 768 * 256 + 256 * 256) {
        int e2 = e - 768 * 256;
        wp[e2] = f2bf(proj_w[e2]);
      }
    }
    return;
  }
  __shared__ float tile[32][33];
  const int hw0 = blockIdx.x * 32, c0 = blockIdx.y * 32, b = blockIdx.z;
  const int tx = threadIdx.x & 31, ty = threadIdx.x >> 5;
  const float* xb = x + ((size_t)b * CCH + c0) * HWT + hw0;
#pragma unroll
  for (int i = 0; i < 4; ++i) {
    int c = ty + i * 8;
    tile[c][tx] = xb[(size_t)c * HWT + tx];
  }
  __syncthreads();
  ushort* xo = xt + ((size_t)b * HWT + hw0) * CCH + c0;
#pragma unroll
  for (int i = 0; i < 4; ++i) {
    int hwl = ty + i * 8;
    xo[(size_t)hwl * CCH + tx] = f2bf(tile[tx][hwl]);
  }
}

// ---------------------------------------------------------------------------
// bf16 MFMA GEMM, (MI*32) x 128 tile, BK=32, 4 waves (2x2), 16x16x32 frags.
// A rows = M dim (weights), B rows = N dim (per-batch activation).
// MODE 0 (qkv, MI=4): epilogue -> fp16; q (bn,hw,d)*scale; v (bn,hw,d);
//   k TRANSPOSED as kT[(bn*8+d/4)][hw][4] for line-merged QK gathers.
// MODE 1 (proj, MI=2): epilogue -> fp32 out (b,o,hw) + bias. 200 blocks.
// ---------------------------------------------------------------------------
template <int MODE, int MI>
__global__ __launch_bounds__(256) void mfma_gemm_k(
    const ushort* __restrict__ A, int rowsA,
    const ushort* __restrict__ B, int rowsB,
    const float* __restrict__ biasv, void* __restrict__ outp) {
  __shared__ ushort Alds[MI * 32 * 32];
  __shared__ ushort Blds[128 * 32];

  const int t  = threadIdx.x;
  const int m0 = blockIdx.y * (MI * 32);
  const int n0 = blockIdx.x * 128;
  const int b  = blockIdx.z;

  const ushort* Ab = A;
  const ushort* Bb = B + (size_t)b * HWT * CCH;

  const int lane  = t & 63;
  const int wid   = t >> 6;
  const int wm    = (wid >> 1) * (MI * 16);
  const int wn    = (wid & 1) * 64;
  const int lrow  = lane & 15;
  const int cwant = lane >> 4;
  const int csw   = (cwant ^ ((lrow >> 1) & 3)) * 8;

  const int srow   = t >> 2;
  const int scslot = t & 3;
  const int wlds   = wid << 9;

  f32x4 acc[MI][4];
#pragma unroll
  for (int i = 0; i < MI; ++i)
#pragma unroll
    for (int j = 0; j < 4; ++j) acc[i][j] = (f32x4){0.f, 0.f, 0.f, 0.f};

  for (int k0 = 0; k0 < CCH; k0 += 32) {
    __syncthreads();
#pragma unroll
    for (int h = 0; h < MI / 2; ++h) {   // A halves
      const int lr   = srow + h * 64;
      const int csrc = (scslot ^ ((lr >> 1) & 3)) * 8;
      int ga = m0 + lr; ga = ga < rowsA ? ga : rowsA - 1;
      const ushort* gpa = Ab + (size_t)ga * CCH + k0 + csrc;
      ushort* lpa = Alds + h * 2048 + wlds;
      __builtin_amdgcn_global_load_lds(
          (const __attribute__((address_space(1))) void*)gpa,
          (__attribute__((address_space(3))) void*)lpa, 16, 0, 0);
    }
#pragma unroll
    for (int h = 0; h < 2; ++h) {        // B halves
      const int lr   = srow + h * 64;
      const int csrc = (scslot ^ ((lr >> 1) & 3)) * 8;
      int gb = n0 + lr; gb = gb < rowsB ? gb : rowsB - 1;
      const ushort* gpb = Bb + (size_t)gb * CCH + k0 + csrc;
      ushort* lpb = Blds + h * 2048 + wlds;
      __builtin_amdgcn_global_load_lds(
          (const __attribute__((address_space(1))) void*)gpb,
          (__attribute__((address_space(3))) void*)lpb, 16, 0, 0);
    }
    __syncthreads();

    short8 af[MI], bf[4];
#pragma unroll
    for (int mi = 0; mi < MI; ++mi)
      af[mi] = *(const short8*)&Alds[(wm + mi * 16 + lrow) * 32 + csw];
#pragma unroll
    for (int ni = 0; ni < 4; ++ni)
      bf[ni] = *(const short8*)&Blds[(wn + ni * 16 + lrow) * 32 + csw];
#pragma unroll
    for (int mi = 0; mi < MI; ++mi)
#pragma unroll
      for (int ni = 0; ni < 4; ++ni)
        acc[mi][ni] = __builtin_amdgcn_mfma_f32_16x16x32_bf16(
            af[mi], bf[ni], acc[mi][ni], 0, 0, 0);
  }

  const int row4 = (lane >> 4) * 4;
  if (MODE == 0) {
    _Float16* qh = (_Float16*)outp;
#pragma unroll
    for (int mi = 0; mi < MI; ++mi) {
      const int o0 = m0 + wm + mi * 16 + row4;   // quad of consecutive o
      const int t3 = o0 >> 8, c0 = o0 & 255;
      const int head = c0 >> 5, d0 = c0 & 31;
      const float sc = (t3 == 0) ? SCALE : 1.f;
      float bv[4];
#pragma unroll
      for (int r = 0; r < 4; ++r) bv[r] = biasv[o0 + r];
      if (t3 == 1) {
        // kT: ((bn*8 + d0/4) * HWT + hw) * 4
        _Float16* base = qh + (size_t)QKV_ELEMS +
                         ((size_t)(b * NH + head) * 8 + (d0 >> 2)) * (HWT * 4);
#pragma unroll
        for (int ni = 0; ni < 4; ++ni) {
          const int hw = n0 + wn + ni * 16 + lrow;
          if (hw < HWT) {
            half4v pack;
#pragma unroll
            for (int r = 0; r < 4; ++r)
              pack[r] = (_Float16)(acc[mi][ni][r] + bv[r]);
            *(half4v*)(base + (size_t)hw * 4) = pack;
          }
        }
      } else {
        _Float16* base = qh + (size_t)t3 * QKV_ELEMS +
                         (size_t)(b * NH + head) * HWT * 32 + d0;
#pragma unroll
        for (int ni = 0; ni < 4; ++ni) {
          const int hw = n0 + wn + ni * 16 + lrow;
          if (hw < HWT) {
            half4v pack;
#pragma unroll
            for (int r = 0; r < 4; ++r)
              pack[r] = (_Float16)((acc[mi][ni][r] + bv[r]) * sc);
            *(half4v*)(base + (size_t)hw * 32) = pack;
          }
        }
      }
    }
  } else {
    float* op = (float*)outp;
#pragma unroll
    for (int mi = 0; mi < MI; ++mi)
#pragma unroll
      for (int r = 0; r < 4; ++r) {
        const int o = m0 + wm + mi * 16 + row4 + r;
        const float bvv = biasv[o];
#pragma unroll
        for (int ni = 0; ni < 4; ++ni) {
          const int hw = n0 + wn + ni * 16 + lrow;
          if (hw < HWT)
            op[((size_t)b * CCH + o) * HWT + hw] = acc[mi][ni][r] + bvv;
        }
      }
  }
}

// ---------------------------------------------------------------------------
// Fused attention: block = 32 pixels x one (b,n); 256 threads; grid 1568.
// Phase A: wave-per-pixel QK; lane = neighbor j; K read from TRANSPOSED
//   kT[(d/4)][hw][4] -> lanes' s are consecutive -> ~7 lines per instr.
// Phase B: 8 threads/pixel PV (4 channels each) from row-major V.
// NOTE (R6 probe): launched 5x this round, idempotent — measures its own
// duration + launch gap via dur delta: dur = base + 4*(attn + gap).
// ---------------------------------------------------------------------------
__global__ __launch_bounds__(256) void attn_fused_k(
    const _Float16* __restrict__ q_h, const _Float16* __restrict__ kt4,
    const _Float16* __restrict__ v_h, const float* __restrict__ relbias,
    ushort* __restrict__ att_t) {
  // bijective XCD swizzle (1568 % 8 == 0)
  const int id  = blockIdx.x;
  const int idx = (id & 7) * 196 + (id >> 3);
  const int bn  = idx / 98;
  const int px0 = (idx % 98) * 32;
  const int b = bn >> 3, n = bn & 7;

  __shared__ float bias_s[169];
  __shared__ uint32_t as_lds[32 * 49];

  const int tid = threadIdx.x;
  if (tid < 169) bias_s[tid] = relbias[tid * NH + n];
  __syncthreads();

  const int wid = tid >> 6, lane = tid & 63;
  const _Float16* ktb = kt4 + (size_t)bn * HWT * 32;  // (8 dq, HWT, 4)

#pragma unroll 2
  for (int pass = 0; pass < 8; ++pass) {
    const int pxl = pass * 4 + wid;
    const int px = px0 + pxl;
    const int h = px / WIMG, w = px % WIMG;
    int ph = h - 3; ph = ph < 0 ? 0 : (ph > 49 ? 49 : ph);
    int pw = w - 3; pw = pw < 0 ? 0 : (pw > 49 ? 49 : pw);
    const int l = ph * 50 + pw;
    const int bih = (h < 3) ? h : ((h < 53) ? 3 : h - 49);
    const int biw = (w < 3) ? w : ((w < 53) ? 3 : w - 49);
    const int bbase = bih * 13 + biw;

    union V64 { uint4 u[4]; half2v hv[16]; };
    V64 Q;   // wave-uniform broadcast load
    const uint4* qp = (const uint4*)(q_h + ((size_t)bn * HWT + px) * 32);
#pragma unroll
    for (int i = 0; i < 4; ++i) Q.u[i] = qp[i];

    if (lane < 49) {
      const int f = l * 49 + lane;
      const int sp = f / 2500;
      const int pos = f - sp * 2500;
      const int si = pos / 50;
      const int sj = pos - si * 50;
      const int s = (si + sp / 7) * WIMG + sj + sp % 7;

      float a0 = 0.f, a1 = 0.f, a2 = 0.f, a3 = 0.f;
#pragma unroll
      for (int dq = 0; dq < 8; ++dq) {
        union { half4v k4; half2v k2[2]; } K;
        K.k4 = *(const half4v*)(ktb + ((size_t)dq * HWT + s) * 4);
#if HAVE_FDOT2
        if (dq & 1) {
          a2 = __builtin_amdgcn_fdot2(K.k2[0], Q.hv[2 * dq], a2, false);
          a3 = __builtin_amdgcn_fdot2(K.k2[1], Q.hv[2 * dq + 1], a3, false);
        } else {
          a0 = __builtin_amdgcn_fdot2(K.k2[0], Q.hv[2 * dq], a0, false);
          a1 = __builtin_amdgcn_fdot2(K.k2[1], Q.hv[2 * dq + 1], a1, false);
        }
#else
        a0 += (float)K.k2[0][0] * (float)Q.hv[2*dq][0];
        a1 += (float)K.k2[0][1] * (float)Q.hv[2*dq][1];
        a2 += (float)K.k2[1][0] * (float)Q.hv[2*dq+1][0];
        a3 += (float)K.k2[1][1] * (float)Q.hv[2*dq+1][1];
#endif
      }
      float a = (a0 + a1) + (a2 + a3);
      a += bias_s[bbase + (lane / 7) * 13 + lane % 7];

      union { _Float16 hh; uint16_t us; } cv;
      cv.hh = (_Float16)a;
      as_lds[pxl * 49 + lane] = ((uint32_t)s << 16) | cv.us;
    }
  }
  __syncthreads();

  // Phase B: thread = (pixel, 4-channel group)
  const int pxb = tid >> 3, oc = tid & 7;
  const _Float16* vb = v_h + (size_t)bn * HWT * 32 + oc * 4;
  const uint32_t* arow = &as_lds[pxb * 49];

  float acc[4] = {0.f, 0.f, 0.f, 0.f};
#pragma unroll 7
  for (int j = 0; j < 49; ++j) {
    const uint32_t u = arow[j];
    union { uint16_t us; _Float16 hh; } cv;
    cv.us = (uint16_t)(u & 0xffffu);
    const float a = (float)cv.hh;
    const int s = (int)(u >> 16);
    const half4v v = *(const half4v*)(vb + (size_t)s * 32);
#pragma unroll
    for (int d = 0; d < 4; ++d) acc[d] += a * (float)v[d];
  }

  ushort tmp[4];
#pragma unroll
  for (int d = 0; d < 4; ++d) tmp[d] = f2bf(acc[d]);
  *(short4v*)(att_t + ((size_t)b * HWT + px0 + pxb) * CCH + n * 32 + oc * 4) =
      *(const short4v*)tmp;
}

// ---------------------------------------------------------------------------
extern "C" void kernel_launch(void* const* d_in, const int* in_sizes, int n_in,
                              void* d_out, int out_size, void* d_ws, size_t ws_size,
                              hipStream_t stream) {
  const float* x       = (const float*)d_in[0];
  const float* qkv_w   = (const float*)d_in[1];
  const float* qkv_b   = (const float*)d_in[2];
  const float* proj_w  = (const float*)d_in[3];
  const float* proj_b  = (const float*)d_in[4];
  const float* relbias = (const float*)d_in[5];
  float* out = (float*)d_out;

  char* wsb = (char*)d_ws;
  _Float16* qh  = (_Float16*)wsb;                      // q fp16 (bn,hw,d)
  _Float16* kt4 = qh + (size_t)QKV_ELEMS;              // kT fp16 (bn,d/4,hw,4)
  _Float16* vh  = qh + (size_t)2 * QKV_ELEMS;          // v fp16 (bn,hw,d)
  ushort*   xt  = (ushort*)(wsb + (size_t)3 * QKV_ELEMS * 2); // bf16 (b,hw,c)
  ushort*   wq  = xt + (size_t)QKV_ELEMS;              // bf16 768x256
  ushort*   wp  = wq + 768 * 256;                      // bf16 256x256
  ushort*   att_t = xt;  // alias: xt fully consumed by qkv GEMM first

  hipLaunchKernelGGL(prep_k, dim3(98, 8, 3), dim3(256), 0, stream,
                     x, qkv_w, proj_w, xt, wq, wp);
  // qkv: A=wq (m=o, 768 rows), B=xt (n=hw) -> fp16 q/kT/v
  hipLaunchKernelGGL((mfma_gemm_k<0, 4>), dim3(25, 6, 2), dim3(256), 0, stream,
                     wq, 768, xt, HWT, qkv_b, (void*)qh);
  // R6 PROBE: 5x identical, idempotent attention launches.
  // dur_us = base + 4*(attn_dur + launch_gap); same output bits.
  for (int rep = 0; rep < 5; ++rep) {
    hipLaunchKernelGGL(attn_fused_k, dim3(1568), dim3(256), 0, stream,
                       qh, kt4, vh, relbias, att_t);
  }
  // proj: A=wp (m=o, 256 rows, BM=64), B=att_t (n=hw) -> fp32 out
  hipLaunchKernelGGL((mfma_gemm_k<1, 2>), dim3(25, 4, 2), dim3(256), 0, stream,
                     wp, 256, att_t, HWT, proj_b, (void*)out);
}

// Round 8
// 68.939 us; speedup vs baseline: 2.7217x; 2.7217x over previous
//
#include <hip/hip_runtime.h>
#include <cstddef>
#include <cstdint>

#define HWT   3136        // 56*56
#define WIMG  56
#define CCH   256
#define NH    8
#define QKV_ELEMS (16 * HWT * 32)   // per-tensor q/k/v elements
#define SCALE 0.17677669529663687f  // 32^-0.5

typedef __attribute__((ext_vector_type(8))) short short8;
typedef __attribute__((ext_vector_type(4))) short short4v;
typedef __attribute__((ext_vector_type(4))) float f32x4;
typedef _Float16 half2v __attribute__((ext_vector_type(2)));
typedef _Float16 half4v __attribute__((ext_vector_type(4)));

#if defined(__has_builtin)
#if __has_builtin(__builtin_amdgcn_fdot2)
#define HAVE_FDOT2 1
#endif
#endif
#ifndef HAVE_FDOT2
#define HAVE_FDOT2 0
#endif

__device__ __forceinline__ ushort f2bf(float f) {
  union { float f; uint32_t u; } v; v.f = f;
  uint32_t u = v.u;
  u += 0x7fffu + ((u >> 16) & 1u);   // round-to-nearest-even
  return (ushort)(u >> 16);
}

// ---------------------------------------------------------------------------
// prep: z<2 -> transpose x (b,c,hw) f32 -> xt (b,hw,c) bf16 (32x32 LDS tile)
//       z==2 -> convert qkv_w / proj_w to bf16
// ---------------------------------------------------------------------------
__global__ __launch_bounds__(256) void prep_k(
    const float* __restrict__ x, const float* __restrict__ qkv_w,
    const float* __restrict__ proj_w, ushort* __restrict__ xt,
    ushort* __restrict__ wq, ushort* __restrict__ wp) {
  if (blockIdx.z == 2) {
    int base = ((blockIdx.y * 98 + blockIdx.x) * 256 + threadIdx.x) * 2;
#pragma unroll
    for (int e = base; e < base + 2; ++e) {
      if (e < 768 * 256) wq[e] = f2bf(qkv_w[e]);
      else if (e < 768 * 256 + 256 * 256) {
        int e2 = e - 768 * 256;
        wp[e2] = f2bf(proj_w[e2]);
      }
    }
    return;
  }
  __shared__ float tile[32][33];
  const int hw0 = blockIdx.x * 32, c0 = blockIdx.y * 32, b = blockIdx.z;
  const int tx = threadIdx.x & 31, ty = threadIdx.x >> 5;
  const float* xb = x + ((size_t)b * CCH + c0) * HWT + hw0;
#pragma unroll
  for (int i = 0; i < 4; ++i) {
    int c = ty + i * 8;
    tile[c][tx] = xb[(size_t)c * HWT + tx];
  }
  __syncthreads();
  ushort* xo = xt + ((size_t)b * HWT + hw0) * CCH + c0;
#pragma unroll
  for (int i = 0; i < 4; ++i) {
    int hwl = ty + i * 8;
    xo[(size_t)hwl * CCH + tx] = f2bf(tile[tx][hwl]);
  }
}

// ---------------------------------------------------------------------------
// bf16 MFMA GEMM, (MI*32) x 128 tile, BK=32, 4 waves (2x2), 16x16x32 frags.
// MODE 0 (qkv, MI=4): epilogue -> fp16; q (bn,hw,d)*scale; v (bn,hw,d);
//   k TRANSPOSED as kT8[(bn*4+d/8)][hw][8] for 16B-per-lane QK gathers.
// MODE 1 (proj, MI=2): epilogue -> fp32 out (b,o,hw) + bias.
// ---------------------------------------------------------------------------
template <int MODE, int MI>
__global__ __launch_bounds__(256) void mfma_gemm_k(
    const ushort* __restrict__ A, int rowsA,
    const ushort* __restrict__ B, int rowsB,
    const float* __restrict__ biasv, void* __restrict__ outp) {
  __shared__ ushort Alds[MI * 32 * 32];
  __shared__ ushort Blds[128 * 32];

  const int t  = threadIdx.x;
  const int m0 = blockIdx.y * (MI * 32);
  const int n0 = blockIdx.x * 128;
  const int b  = blockIdx.z;

  const ushort* Ab = A;
  const ushort* Bb = B + (size_t)b * HWT * CCH;

  const int lane  = t & 63;
  const int wid   = t >> 6;
  const int wm    = (wid >> 1) * (MI * 16);
  const int wn    = (wid & 1) * 64;
  const int lrow  = lane & 15;
  const int cwant = lane >> 4;
  const int csw   = (cwant ^ ((lrow >> 1) & 3)) * 8;

  const int srow   = t >> 2;
  const int scslot = t & 3;
  const int wlds   = wid << 9;

  f32x4 acc[MI][4];
#pragma unroll
  for (int i = 0; i < MI; ++i)
#pragma unroll
    for (int j = 0; j < 4; ++j) acc[i][j] = (f32x4){0.f, 0.f, 0.f, 0.f};

  for (int k0 = 0; k0 < CCH; k0 += 32) {
    __syncthreads();
#pragma unroll
    for (int h = 0; h < MI / 2; ++h) {   // A halves
      const int lr   = srow + h * 64;
      const int csrc = (scslot ^ ((lr >> 1) & 3)) * 8;
      int ga = m0 + lr; ga = ga < rowsA ? ga : rowsA - 1;
      const ushort* gpa = Ab + (size_t)ga * CCH + k0 + csrc;
      ushort* lpa = Alds + h * 2048 + wlds;
      __builtin_amdgcn_global_load_lds(
          (const __attribute__((address_space(1))) void*)gpa,
          (__attribute__((address_space(3))) void*)lpa, 16, 0, 0);
    }
#pragma unroll
    for (int h = 0; h < 2; ++h) {        // B halves
      const int lr   = srow + h * 64;
      const int csrc = (scslot ^ ((lr >> 1) & 3)) * 8;
      int gb = n0 + lr; gb = gb < rowsB ? gb : rowsB - 1;
      const ushort* gpb = Bb + (size_t)gb * CCH + k0 + csrc;
      ushort* lpb = Blds + h * 2048 + wlds;
      __builtin_amdgcn_global_load_lds(
          (const __attribute__((address_space(1))) void*)gpb,
          (__attribute__((address_space(3))) void*)lpb, 16, 0, 0);
    }
    __syncthreads();

    short8 af[MI], bf[4];
#pragma unroll
    for (int mi = 0; mi < MI; ++mi)
      af[mi] = *(const short8*)&Alds[(wm + mi * 16 + lrow) * 32 + csw];
#pragma unroll
    for (int ni = 0; ni < 4; ++ni)
      bf[ni] = *(const short8*)&Blds[(wn + ni * 16 + lrow) * 32 + csw];
#pragma unroll
    for (int mi = 0; mi < MI; ++mi)
#pragma unroll
      for (int ni = 0; ni < 4; ++ni)
        acc[mi][ni] = __builtin_amdgcn_mfma_f32_16x16x32_bf16(
            af[mi], bf[ni], acc[mi][ni], 0, 0, 0);
  }

  const int row4 = (lane >> 4) * 4;
  if (MODE == 0) {
    _Float16* qh = (_Float16*)outp;
#pragma unroll
    for (int mi = 0; mi < MI; ++mi) {
      const int o0 = m0 + wm + mi * 16 + row4;   // quad of consecutive o
      const int t3 = o0 >> 8, c0 = o0 & 255;
      const int head = c0 >> 5, d0 = c0 & 31;
      const float sc = (t3 == 0) ? SCALE : 1.f;
      float bv[4];
#pragma unroll
      for (int r = 0; r < 4; ++r) bv[r] = biasv[o0 + r];
      if (t3 == 1) {
        // kT8: ((bn*4 + d0/8) * HWT + hw) * 8 + (d0&7)
        _Float16* base = qh + (size_t)QKV_ELEMS +
                         ((size_t)(b * NH + head) * 4 + (d0 >> 3)) * (HWT * 8) +
                         (d0 & 7);
#pragma unroll
        for (int ni = 0; ni < 4; ++ni) {
          const int hw = n0 + wn + ni * 16 + lrow;
          if (hw < HWT) {
            half4v pack;
#pragma unroll
            for (int r = 0; r < 4; ++r)
              pack[r] = (_Float16)(acc[mi][ni][r] + bv[r]);
            *(half4v*)(base + (size_t)hw * 8) = pack;
          }
        }
      } else {
        _Float16* base = qh + (size_t)t3 * QKV_ELEMS +
                         (size_t)(b * NH + head) * HWT * 32 + d0;
#pragma unroll
        for (int ni = 0; ni < 4; ++ni) {
          const int hw = n0 + wn + ni * 16 + lrow;
          if (hw < HWT) {
            half4v pack;
#pragma unroll
            for (int r = 0; r < 4; ++r)
              pack[r] = (_Float16)((acc[mi][ni][r] + bv[r]) * sc);
            *(half4v*)(base + (size_t)hw * 32) = pack;
          }
        }
      }
    }
  } else {
    float* op = (float*)outp;
#pragma unroll
    for (int mi = 0; mi < MI; ++mi)
#pragma unroll
      for (int r = 0; r < 4; ++r) {
        const int o = m0 + wm + mi * 16 + row4 + r;
        const float bvv = biasv[o];
#pragma unroll
        for (int ni = 0; ni < 4; ++ni) {
          const int hw = n0 + wn + ni * 16 + lrow;
          if (hw < HWT)
            op[((size_t)b * CCH + o) * HWT + hw] = acc[mi][ni][r] + bvv;
        }
      }
  }
}

// ---------------------------------------------------------------------------
// attn_v3: barrier-free, LDS-free. 3136 blocks x 4 waves; wave = 4 pixels.
// Phase A (per px): lane = neighbor j (j>=49 clamped, weight zeroed);
//   K via kT8 (4 x 16B loads: slice dq holds d = 8dq..8dq+7), bias direct
//   from global; score kept packed in a register (s<<16 | f16(a)).
// Phase B (per px): lane = (j8, oc); score/src via one __shfl per j-group;
//   7 independent 8B V-loads; shfl_xor reduce over j8; bf16 store (b,hw,c).
// ---------------------------------------------------------------------------
__global__ __launch_bounds__(256, 4) void attn_v3_k(
    const _Float16* __restrict__ q_h, const _Float16* __restrict__ kt8,
    const _Float16* __restrict__ v_h, const float* __restrict__ relbias,
    ushort* __restrict__ att_t) {
  // bijective XCD swizzle (3136 % 8 == 0): each XCD owns 2 (b,n) slices
  const int id  = blockIdx.x;
  const int idx = (id & 7) * 392 + (id >> 3);
  const int bn  = idx / 196;
  const int g   = idx % 196;
  const int b = bn >> 3, n = bn & 7;

  const int tid = threadIdx.x;
  const int wid = tid >> 6, lane = tid & 63;
  const int px0 = g * 16 + wid * 4;

  const _Float16* kb = kt8 + (size_t)bn * 4 * HWT * 8;
  const _Float16* vb = v_h + (size_t)bn * HWT * 32;
  const _Float16* qb = q_h + (size_t)bn * HWT * 32;

  uint32_t pa[4];

  // ---- Phase A: scores for 4 pixels, fully unrolled (loads overlap) ----
#pragma unroll
  for (int pi = 0; pi < 4; ++pi) {
    const int px = px0 + pi;
    const int h = px / WIMG, w = px % WIMG;
    int ph = h - 3; ph = ph < 0 ? 0 : (ph > 49 ? 49 : ph);
    int pw = w - 3; pw = pw < 0 ? 0 : (pw > 49 ? 49 : pw);
    const int l = ph * 50 + pw;
    const int bih = (h < 3) ? h : ((h < 53) ? 3 : h - 49);
    const int biw = (w < 3) ? w : ((w < 53) ? 3 : w - 49);

    const int jc = lane < 49 ? lane : 48;
    const int f = l * 49 + jc;
    const int sp = f / 2500;
    const int pos = f - sp * 2500;
    const int si = pos / 50;
    const int sj = pos - si * 50;
    const int s = (si + sp / 7) * WIMG + sj + sp % 7;

    // K: 4 independent 16B loads (kT8 slices); slice dq = d 8dq..8dq+7
    union V16 { uint4 u; half2v h2[4]; };
    V16 K0, K1, K2, K3;
    K0.u = *(const uint4*)(kb + ((size_t)0 * HWT + s) * 8);
    K1.u = *(const uint4*)(kb + ((size_t)1 * HWT + s) * 8);
    K2.u = *(const uint4*)(kb + ((size_t)2 * HWT + s) * 8);
    K3.u = *(const uint4*)(kb + ((size_t)3 * HWT + s) * 8);
    // Q: 64B lane-uniform; Q.hv[i] = d 2i..2i+1
    union V64 { uint4 u[4]; half2v hv[16]; };
    V64 Q;
    const uint4* qp = (const uint4*)(qb + (size_t)px * 32);
#pragma unroll
    for (int i = 0; i < 4; ++i) Q.u[i] = qp[i];
    // bias: direct global (L1/L2-resident 5.4KB table)
    const float bvv =
        relbias[(size_t)(bih * 13 + biw + (jc / 7) * 13 + jc % 7) * NH + n];

    float a0 = 0.f, a1 = 0.f, a2 = 0.f, a3 = 0.f;
#if HAVE_FDOT2
#pragma unroll
    for (int i = 0; i < 4; ++i) {
      a0 = __builtin_amdgcn_fdot2(K0.h2[i], Q.hv[i],      a0, false);
      a1 = __builtin_amdgcn_fdot2(K1.h2[i], Q.hv[4 + i],  a1, false);
      a2 = __builtin_amdgcn_fdot2(K2.h2[i], Q.hv[8 + i],  a2, false);
      a3 = __builtin_amdgcn_fdot2(K3.h2[i], Q.hv[12 + i], a3, false);
    }
#else
#pragma unroll
    for (int i = 0; i < 4; ++i) {
      a0 += (float)K0.h2[i][0] * (float)Q.hv[i][0] +
            (float)K0.h2[i][1] * (float)Q.hv[i][1];
      a1 += (float)K1.h2[i][0] * (float)Q.hv[4 + i][0] +
            (float)K1.h2[i][1] * (float)Q.hv[4 + i][1];
      a2 += (float)K2.h2[i][0] * (float)Q.hv[8 + i][0] +
            (float)K2.h2[i][1] * (float)Q.hv[8 + i][1];
      a3 += (float)K3.h2[i][0] * (float)Q.hv[12 + i][0] +
            (float)K3.h2[i][1] * (float)Q.hv[12 + i][1];
    }
#endif
    const float a = (a0 + a1) + (a2 + a3) + bvv;

    union { _Float16 hh; uint16_t us; } cv;
    cv.hh = (_Float16)a;
    pa[pi] = ((uint32_t)s << 16) | (lane < 49 ? (uint32_t)cv.us : 0u);
  }

  // ---- Phase B: PV for 4 pixels; lane = (j8 = lane>>3, oc = lane&7) ----
  const int oc = lane & 7, j8 = lane >> 3;
#pragma unroll
  for (int pi = 0; pi < 4; ++pi) {
    const int px = px0 + pi;
    float c0 = 0.f, c1 = 0.f, c2 = 0.f, c3 = 0.f;
#pragma unroll
    for (int jj = 0; jj < 7; ++jj) {
      const int j = jj * 8 + j8;             // 0..55 (>=49 has a==0)
      const uint32_t u = __shfl(pa[pi], j);
      union { uint16_t us; _Float16 hh; } cv;
      cv.us = (uint16_t)(u & 0xffffu);
      const float a = (float)cv.hh;
      const int s = (int)(u >> 16);
      const half4v v = *(const half4v*)(vb + (size_t)s * 32 + oc * 4);
      c0 += a * (float)v[0];
      c1 += a * (float)v[1];
      c2 += a * (float)v[2];
      c3 += a * (float)v[3];
    }
#pragma unroll
    for (int m = 8; m <= 32; m <<= 1) {
      c0 += __shfl_xor(c0, m);
      c1 += __shfl_xor(c1, m);
      c2 += __shfl_xor(c2, m);
      c3 += __shfl_xor(c3, m);
    }
    if (j8 == 0) {
      ushort tmp[4];
      tmp[0] = f2bf(c0); tmp[1] = f2bf(c1);
      tmp[2] = f2bf(c2); tmp[3] = f2bf(c3);
      *(short4v*)(att_t + ((size_t)b * HWT + px) * CCH + n * 32 + oc * 4) =
          *(const short4v*)tmp;
    }
  }
}

// ---------------------------------------------------------------------------
extern "C" void kernel_launch(void* const* d_in, const int* in_sizes, int n_in,
                              void* d_out, int out_size, void* d_ws, size_t ws_size,
                              hipStream_t stream) {
  const float* x       = (const float*)d_in[0];
  const float* qkv_w   = (const float*)d_in[1];
  const float* qkv_b   = (const float*)d_in[2];
  const float* proj_w  = (const float*)d_in[3];
  const float* proj_b  = (const float*)d_in[4];
  const float* relbias = (const float*)d_in[5];
  float* out = (float*)d_out;

  char* wsb = (char*)d_ws;
  _Float16* qh  = (_Float16*)wsb;                      // q fp16 (bn,hw,d)
  _Float16* kt8 = qh + (size_t)QKV_ELEMS;              // kT fp16 (bn,d/8,hw,8)
  _Float16* vh  = qh + (size_t)2 * QKV_ELEMS;          // v fp16 (bn,hw,d)
  ushort*   xt  = (ushort*)(wsb + (size_t)3 * QKV_ELEMS * 2); // bf16 (b,hw,c)
  ushort*   wq  = xt + (size_t)QKV_ELEMS;              // bf16 768x256
  ushort*   wp  = wq + 768 * 256;                      // bf16 256x256
  ushort*   att_t = xt;  // alias: xt fully consumed by qkv GEMM first

  hipLaunchKernelGGL(prep_k, dim3(98, 8, 3), dim3(256), 0, stream,
                     x, qkv_w, proj_w, xt, wq, wp);
  // qkv: A=wq (m=o, 768 rows), B=xt (n=hw) -> fp16 q/kT8/v
  hipLaunchKernelGGL((mfma_gemm_k<0, 4>), dim3(25, 6, 2), dim3(256), 0, stream,
                     wq, 768, xt, HWT, qkv_b, (void*)qh);
  hipLaunchKernelGGL(attn_v3_k, dim3(3136), dim3(256), 0, stream,
                     qh, kt8, vh, relbias, att_t);
  // proj: A=wp (m=o, 256 rows, BM=64), B=att_t (n=hw) -> fp32 out
  hipLaunchKernelGGL((mfma_gemm_k<1, 2>), dim3(25, 4, 2), dim3(256), 0, stream,
                     wp, 256, att_t, HWT, proj_b, (void*)out);
}

// Round 9
// 59.537 us; speedup vs baseline: 3.1514x; 1.1579x over previous
//
#include <hip/hip_runtime.h>
#include <cstddef>
#include <cstdint>

#define HWT   3136        // 56*56
#define WIMG  56
#define CCH   256
#define NH    8
#define QKV_ELEMS (16 * HWT * 32)   // per-tensor q/k/v elements
#define SCALE 0.17677669529663687f  // 32^-0.5

typedef __attribute__((ext_vector_type(8))) short short8;
typedef __attribute__((ext_vector_type(4))) short short4v;
typedef __attribute__((ext_vector_type(4))) float f32x4;
typedef _Float16 half2v __attribute__((ext_vector_type(2)));
typedef _Float16 half4v __attribute__((ext_vector_type(4)));

#if defined(__has_builtin)
#if __has_builtin(__builtin_amdgcn_fdot2)
#define HAVE_FDOT2 1
#endif
#endif
#ifndef HAVE_FDOT2
#define HAVE_FDOT2 0
#endif

__device__ __forceinline__ ushort f2bf(float f) {
  union { float f; uint32_t u; } v; v.f = f;
  uint32_t u = v.u;
  u += 0x7fffu + ((u >> 16) & 1u);   // round-to-nearest-even
  return (ushort)(u >> 16);
}

// ---------------------------------------------------------------------------
// prep: z<2  -> transpose x (b,c,hw) f32 -> xt (b,hw,c) bf16
//       z==2 -> convert qkv_w / proj_w to bf16
//       z==3 -> build src16 table: src16[f] for f = l*49+k (reshape-
//               reinterpret semantics): sp=f/2500, pos=f%2500,
//               s = (pos/50 + sp/7)*56 + pos%50 + sp%7
// ---------------------------------------------------------------------------
__global__ __launch_bounds__(256) void prep_k(
    const float* __restrict__ x, const float* __restrict__ qkv_w,
    const float* __restrict__ proj_w, ushort* __restrict__ xt,
    ushort* __restrict__ wq, ushort* __restrict__ wp,
    ushort* __restrict__ src16) {
  if (blockIdx.z == 3) {
    int e = (blockIdx.y * 98 + blockIdx.x) * 256 + threadIdx.x;
    if (e < 2500 * 49) {
      int sp = e / 2500;
      int pos = e - sp * 2500;
      int i = pos / 50 + sp / 7;
      int j = pos % 50 + sp % 7;
      src16[e] = (ushort)(i * WIMG + j);
    }
    return;
  }
  if (blockIdx.z == 2) {
    int base = ((blockIdx.y * 98 + blockIdx.x) * 256 + threadIdx.x) * 2;
#pragma unroll
    for (int e = base; e < base + 2; ++e) {
      if (e < 768 * 256) wq[e] = f2bf(qkv_w[e]);
      else if (e < 768 * 256 + 256 * 256) {
        int e2 = e - 768 * 256;
        wp[e2] = f2bf(proj_w[e2]);
      }
    }
    return;
  }
  __shared__ float tile[32][33];
  const int hw0 = blockIdx.x * 32, c0 = blockIdx.y * 32, b = blockIdx.z;
  const int tx = threadIdx.x & 31, ty = threadIdx.x >> 5;
  const float* xb = x + ((size_t)b * CCH + c0) * HWT + hw0;
#pragma unroll
  for (int i = 0; i < 4; ++i) {
    int c = ty + i * 8;
    tile[c][tx] = xb[(size_t)c * HWT + tx];
  }
  __syncthreads();
  ushort* xo = xt + ((size_t)b * HWT + hw0) * CCH + c0;
#pragma unroll
  for (int i = 0; i < 4; ++i) {
    int hwl = ty + i * 8;
    xo[(size_t)hwl * CCH + tx] = f2bf(tile[tx][hwl]);
  }
}

// ---------------------------------------------------------------------------
// bf16 MFMA GEMM, (MI*32) x 128 tile, BK=32, 4 waves (2x2), 16x16x32 frags.
// MODE 0 (qkv, MI=4): epilogue -> fp16; q (bn,hw,d)*scale; v (bn,hw,d);
//   k TRANSPOSED as kT8[(bn*4+d/8)][hw][8] for 16B-per-lane QK gathers.
// MODE 1 (proj, MI=2): epilogue -> fp32 out (b,o,hw) + bias.
// ---------------------------------------------------------------------------
template <int MODE, int MI>
__global__ __launch_bounds__(256) void mfma_gemm_k(
    const ushort* __restrict__ A, int rowsA,
    const ushort* __restrict__ B, int rowsB,
    const float* __restrict__ biasv, void* __restrict__ outp) {
  __shared__ ushort Alds[MI * 32 * 32];
  __shared__ ushort Blds[128 * 32];

  const int t  = threadIdx.x;
  const int m0 = blockIdx.y * (MI * 32);
  const int n0 = blockIdx.x * 128;
  const int b  = blockIdx.z;

  const ushort* Ab = A;
  const ushort* Bb = B + (size_t)b * HWT * CCH;

  const int lane  = t & 63;
  const int wid   = t >> 6;
  const int wm    = (wid >> 1) * (MI * 16);
  const int wn    = (wid & 1) * 64;
  const int lrow  = lane & 15;
  const int cwant = lane >> 4;
  const int csw   = (cwant ^ ((lrow >> 1) & 3)) * 8;

  const int srow   = t >> 2;
  const int scslot = t & 3;
  const int wlds   = wid << 9;

  f32x4 acc[MI][4];
#pragma unroll
  for (int i = 0; i < MI; ++i)
#pragma unroll
    for (int j = 0; j < 4; ++j) acc[i][j] = (f32x4){0.f, 0.f, 0.f, 0.f};

  for (int k0 = 0; k0 < CCH; k0 += 32) {
    __syncthreads();
#pragma unroll
    for (int h = 0; h < MI / 2; ++h) {   // A halves
      const int lr   = srow + h * 64;
      const int csrc = (scslot ^ ((lr >> 1) & 3)) * 8;
      int ga = m0 + lr; ga = ga < rowsA ? ga : rowsA - 1;
      const ushort* gpa = Ab + (size_t)ga * CCH + k0 + csrc;
      ushort* lpa = Alds + h * 2048 + wlds;
      __builtin_amdgcn_global_load_lds(
          (const __attribute__((address_space(1))) void*)gpa,
          (__attribute__((address_space(3))) void*)lpa, 16, 0, 0);
    }
#pragma unroll
    for (int h = 0; h < 2; ++h) {        // B halves
      const int lr   = srow + h * 64;
      const int csrc = (scslot ^ ((lr >> 1) & 3)) * 8;
      int gb = n0 + lr; gb = gb < rowsB ? gb : rowsB - 1;
      const ushort* gpb = Bb + (size_t)gb * CCH + k0 + csrc;
      ushort* lpb = Blds + h * 2048 + wlds;
      __builtin_amdgcn_global_load_lds(
          (const __attribute__((address_space(1))) void*)gpb,
          (__attribute__((address_space(3))) void*)lpb, 16, 0, 0);
    }
    __syncthreads();

    short8 af[MI], bf[4];
#pragma unroll
    for (int mi = 0; mi < MI; ++mi)
      af[mi] = *(const short8*)&Alds[(wm + mi * 16 + lrow) * 32 + csw];
#pragma unroll
    for (int ni = 0; ni < 4; ++ni)
      bf[ni] = *(const short8*)&Blds[(wn + ni * 16 + lrow) * 32 + csw];
#pragma unroll
    for (int mi = 0; mi < MI; ++mi)
#pragma unroll
      for (int ni = 0; ni < 4; ++ni)
        acc[mi][ni] = __builtin_amdgcn_mfma_f32_16x16x32_bf16(
            af[mi], bf[ni], acc[mi][ni], 0, 0, 0);
  }

  const int row4 = (lane >> 4) * 4;
  if (MODE == 0) {
    _Float16* qh = (_Float16*)outp;
#pragma unroll
    for (int mi = 0; mi < MI; ++mi) {
      const int o0 = m0 + wm + mi * 16 + row4;   // quad of consecutive o
      const int t3 = o0 >> 8, c0 = o0 & 255;
      const int head = c0 >> 5, d0 = c0 & 31;
      const float sc = (t3 == 0) ? SCALE : 1.f;
      float bv[4];
#pragma unroll
      for (int r = 0; r < 4; ++r) bv[r] = biasv[o0 + r];
      if (t3 == 1) {
        // kT8: ((bn*4 + d0/8) * HWT + hw) * 8 + (d0&7)
        _Float16* base = qh + (size_t)QKV_ELEMS +
                         ((size_t)(b * NH + head) * 4 + (d0 >> 3)) * (HWT * 8) +
                         (d0 & 7);
#pragma unroll
        for (int ni = 0; ni < 4; ++ni) {
          const int hw = n0 + wn + ni * 16 + lrow;
          if (hw < HWT) {
            half4v pack;
#pragma unroll
            for (int r = 0; r < 4; ++r)
              pack[r] = (_Float16)(acc[mi][ni][r] + bv[r]);
            *(half4v*)(base + (size_t)hw * 8) = pack;
          }
        }
      } else {
        _Float16* base = qh + (size_t)t3 * QKV_ELEMS +
                         (size_t)(b * NH + head) * HWT * 32 + d0;
#pragma unroll
        for (int ni = 0; ni < 4; ++ni) {
          const int hw = n0 + wn + ni * 16 + lrow;
          if (hw < HWT) {
            half4v pack;
#pragma unroll
            for (int r = 0; r < 4; ++r)
              pack[r] = (_Float16)((acc[mi][ni][r] + bv[r]) * sc);
            *(half4v*)(base + (size_t)hw * 32) = pack;
          }
        }
      }
    }
  } else {
    float* op = (float*)outp;
#pragma unroll
    for (int mi = 0; mi < MI; ++mi)
#pragma unroll
      for (int r = 0; r < 4; ++r) {
        const int o = m0 + wm + mi * 16 + row4 + r;
        const float bvv = biasv[o];
#pragma unroll
        for (int ni = 0; ni < 4; ++ni) {
          const int hw = n0 + wn + ni * 16 + lrow;
          if (hw < HWT)
            op[((size_t)b * CCH + o) * HWT + hw] = acc[mi][ni][r] + bvv;
        }
      }
  }
}

// ---------------------------------------------------------------------------
// attn_v4: attn_fused skeleton (measured best) + src16 table + batched loads.
// Block = 32 px x one (b,n), 256 thr, grid 1568 (XCD-swizzled).
// Phase A: wave w owns px [w*8, w*8+8); processed in 4 batches of 2 px:
//   per batch, issue 2 src16 loads + 8 kT8 loads, then 2x16 fdot2;
//   score packed (s<<16 | f16(a)) -> LDS.
// Phase B: thread = (px, oc=4ch); j in 7 groups of 7: 7 LDS reads ->
//   7 independent 8B V loads -> 28 FMA. f32 accum, bf16 store (b,hw,c).
// ---------------------------------------------------------------------------
__global__ __launch_bounds__(256, 4) void attn_v4_k(
    const _Float16* __restrict__ q_h, const _Float16* __restrict__ kt8,
    const _Float16* __restrict__ v_h, const float* __restrict__ relbias,
    const ushort* __restrict__ src16, ushort* __restrict__ att_t) {
  // bijective XCD swizzle (1568 % 8 == 0)
  const int id  = blockIdx.x;
  const int idx = (id & 7) * 196 + (id >> 3);
  const int bn  = idx / 98;
  const int g   = idx % 98;
  const int px0 = g * 32;
  const int b = bn >> 3, n = bn & 7;

  __shared__ float bias_s[169];
  __shared__ uint32_t as_lds[32 * 49];

  const int tid = threadIdx.x;
  if (tid < 169) bias_s[tid] = relbias[tid * NH + n];
  __syncthreads();

  const int wid = tid >> 6, lane = tid & 63;
  const int jc = lane < 49 ? lane : 48;
  const int jbias = (jc / 7) * 13 + jc % 7;   // per-lane constant

  const _Float16* kb = kt8 + (size_t)bn * 4 * HWT * 8;
  const _Float16* vb = v_h + (size_t)bn * HWT * 32;
  const _Float16* qb = q_h + (size_t)bn * HWT * 32;

  const int pxw = px0 + wid * 8;

#pragma unroll
  for (int batch = 0; batch < 4; ++batch) {
    // ---- load stage: 2 src + 8 K loads in flight ----
    int sv[2], bb[2];
#pragma unroll
    for (int p = 0; p < 2; ++p) {
      const int px = pxw + batch * 2 + p;          // wave-uniform -> SALU
      const int h = px / WIMG, w = px % WIMG;
      int ph = h - 3; ph = ph < 0 ? 0 : (ph > 49 ? 49 : ph);
      int pw = w - 3; pw = pw < 0 ? 0 : (pw > 49 ? 49 : pw);
      const int l = ph * 50 + pw;
      const int bih = (h < 3) ? h : ((h < 53) ? 3 : h - 49);
      const int biw = (w < 3) ? w : ((w < 53) ? 3 : w - 49);
      bb[p] = bih * 13 + biw;
      sv[p] = (int)src16[l * 49 + jc];             // coalesced 98B run
    }
    union V16 { uint4 u; half2v h2[4]; };
    V16 K[2][4];
#pragma unroll
    for (int p = 0; p < 2; ++p)
#pragma unroll
      for (int dq = 0; dq < 4; ++dq)
        K[p][dq].u = *(const uint4*)(kb + ((size_t)dq * HWT + sv[p]) * 8);

    // ---- math stage ----
#pragma unroll
    for (int p = 0; p < 2; ++p) {
      const int px = pxw + batch * 2 + p;
      union V64 { uint4 u[4]; half2v hv[16]; };
      V64 Q;                                        // uniform -> scalar loads
      const uint4* qp = (const uint4*)(qb + (size_t)px * 32);
#pragma unroll
      for (int i = 0; i < 4; ++i) Q.u[i] = qp[i];
      const float bvv = bias_s[bb[p] + jbias];

      float a0 = 0.f, a1 = 0.f, a2 = 0.f, a3 = 0.f;
#if HAVE_FDOT2
#pragma unroll
      for (int i = 0; i < 4; ++i) {
        a0 = __builtin_amdgcn_fdot2(K[p][0].h2[i], Q.hv[i],      a0, false);
        a1 = __builtin_amdgcn_fdot2(K[p][1].h2[i], Q.hv[4 + i],  a1, false);
        a2 = __builtin_amdgcn_fdot2(K[p][2].h2[i], Q.hv[8 + i],  a2, false);
        a3 = __builtin_amdgcn_fdot2(K[p][3].h2[i], Q.hv[12 + i], a3, false);
      }
#else
#pragma unroll
      for (int i = 0; i < 4; ++i) {
        a0 += (float)K[p][0].h2[i][0] * (float)Q.hv[i][0] +
              (float)K[p][0].h2[i][1] * (float)Q.hv[i][1];
        a1 += (float)K[p][1].h2[i][0] * (float)Q.hv[4 + i][0] +
              (float)K[p][1].h2[i][1] * (float)Q.hv[4 + i][1];
        a2 += (float)K[p][2].h2[i][0] * (float)Q.hv[8 + i][0] +
              (float)K[p][2].h2[i][1] * (float)Q.hv[8 + i][1];
        a3 += (float)K[p][3].h2[i][0] * (float)Q.hv[12 + i][0] +
              (float)K[p][3].h2[i][1] * (float)Q.hv[12 + i][1];
      }
#endif
      const float a = (a0 + a1) + (a2 + a3) + bvv;
      union { _Float16 hh; uint16_t us; } cv;
      cv.hh = (_Float16)a;
      if (lane < 49)
        as_lds[(pxw - px0 + batch * 2 + p) * 49 + lane] =
            ((uint32_t)sv[p] << 16) | cv.us;
    }
  }
  __syncthreads();

  // ---- Phase B: thread = (px, oc); 7 groups of 7 j's ----
  const int pxb = tid >> 3, oc = tid & 7;
  const uint32_t* arow = &as_lds[pxb * 49];
  const _Float16* vbase = vb + oc * 4;

  float c0 = 0.f, c1 = 0.f, c2 = 0.f, c3 = 0.f;
#pragma unroll
  for (int gq = 0; gq < 7; ++gq) {
    uint32_t u[7];
#pragma unroll
    for (int i = 0; i < 7; ++i) u[i] = arow[gq * 7 + i];
    half4v vv[7];
#pragma unroll
    for (int i = 0; i < 7; ++i)
      vv[i] = *(const half4v*)(vbase + (size_t)(u[i] >> 16) * 32);
#pragma unroll
    for (int i = 0; i < 7; ++i) {
      union { uint16_t us; _Float16 hh; } cv;
      cv.us = (uint16_t)(u[i] & 0xffffu);
      const float a = (float)cv.hh;
      c0 += a * (float)vv[i][0];
      c1 += a * (float)vv[i][1];
      c2 += a * (float)vv[i][2];
      c3 += a * (float)vv[i][3];
    }
  }

  ushort tmp[4];
  tmp[0] = f2bf(c0); tmp[1] = f2bf(c1);
  tmp[2] = f2bf(c2); tmp[3] = f2bf(c3);
  *(short4v*)(att_t + ((size_t)b * HWT + px0 + pxb) * CCH + n * 32 + oc * 4) =
      *(const short4v*)tmp;
}

// ---------------------------------------------------------------------------
extern "C" void kernel_launch(void* const* d_in, const int* in_sizes, int n_in,
                              void* d_out, int out_size, void* d_ws, size_t ws_size,
                              hipStream_t stream) {
  const float* x       = (const float*)d_in[0];
  const float* qkv_w   = (const float*)d_in[1];
  const float* qkv_b   = (const float*)d_in[2];
  const float* proj_w  = (const float*)d_in[3];
  const float* proj_b  = (const float*)d_in[4];
  const float* relbias = (const float*)d_in[5];
  float* out = (float*)d_out;

  char* wsb = (char*)d_ws;
  _Float16* qh  = (_Float16*)wsb;                      // q fp16 (bn,hw,d)
  _Float16* kt8 = qh + (size_t)QKV_ELEMS;              // kT fp16 (bn,d/8,hw,8)
  _Float16* vh  = qh + (size_t)2 * QKV_ELEMS;          // v fp16 (bn,hw,d)
  ushort*   xt  = (ushort*)(wsb + (size_t)3 * QKV_ELEMS * 2); // bf16 (b,hw,c)
  ushort*   wq  = xt + (size_t)QKV_ELEMS;              // bf16 768x256
  ushort*   wp  = wq + 768 * 256;                      // bf16 256x256
  ushort*   src16 = wp + 256 * 256;                    // u16, 2500*49
  ushort*   att_t = xt;  // alias: xt fully consumed by qkv GEMM first

  hipLaunchKernelGGL(prep_k, dim3(98, 8, 4), dim3(256), 0, stream,
                     x, qkv_w, proj_w, xt, wq, wp, src16);
  // qkv: A=wq (m=o, 768 rows), B=xt (n=hw) -> fp16 q/kT8/v
  hipLaunchKernelGGL((mfma_gemm_k<0, 4>), dim3(25, 6, 2), dim3(256), 0, stream,
                     wq, 768, xt, HWT, qkv_b, (void*)qh);
  hipLaunchKernelGGL(attn_v4_k, dim3(1568), dim3(256), 0, stream,
                     qh, kt8, vh, relbias, src16, att_t);
  // proj: A=wp (m=o, 256 rows, BM=64), B=att_t (n=hw) -> fp32 out
  hipLaunchKernelGGL((mfma_gemm_k<1, 2>), dim3(25, 4, 2), dim3(256), 0, stream,
                     wp, 256, att_t, HWT, proj_b, (void*)out);
}

// Round 11
// 54.278 us; speedup vs baseline: 3.4568x; 1.0969x over previous
//
#include <hip/hip_runtime.h>
#include <cstddef>
#include <cstdint>

#define HWT   3136        // 56*56
#define WIMG  56
#define CCH   256
#define NH    8
#define QKV_ELEMS (16 * HWT * 32)   // per-tensor q/k/v elements
#define SCALE 0.17677669529663687f  // 32^-0.5

typedef __attribute__((ext_vector_type(8))) short short8;
typedef __attribute__((ext_vector_type(4))) short short4v;
typedef __attribute__((ext_vector_type(4))) float f32x4;
typedef _Float16 half2v __attribute__((ext_vector_type(2)));
typedef _Float16 half4v __attribute__((ext_vector_type(4)));

#if defined(__has_builtin)
#if __has_builtin(__builtin_amdgcn_fdot2)
#define HAVE_FDOT2 1
#endif
#endif
#ifndef HAVE_FDOT2
#define HAVE_FDOT2 0
#endif

__device__ __forceinline__ ushort f2bf(float f) {
  union { float f; uint32_t u; } v; v.f = f;
  uint32_t u = v.u;
  u += 0x7fffu + ((u >> 16) & 1u);   // round-to-nearest-even
  return (ushort)(u >> 16);
}

// ---------------------------------------------------------------------------
// prep: z<2  -> transpose x (b,c,hw) f32 -> xt (b,hw,c) bf16
//       z==2 -> convert qkv_w / proj_w to bf16
//       z==3 -> build src16 table (reshape-reinterpret semantics)
// ---------------------------------------------------------------------------
__global__ __launch_bounds__(256) void prep_k(
    const float* __restrict__ x, const float* __restrict__ qkv_w,
    const float* __restrict__ proj_w, ushort* __restrict__ xt,
    ushort* __restrict__ wq, ushort* __restrict__ wp,
    ushort* __restrict__ src16) {
  if (blockIdx.z == 3) {
    int e = (blockIdx.y * 98 + blockIdx.x) * 256 + threadIdx.x;
    if (e < 2500 * 49) {
      int sp = e / 2500;
      int pos = e - sp * 2500;
      int i = pos / 50 + sp / 7;
      int j = pos % 50 + sp % 7;
      src16[e] = (ushort)(i * WIMG + j);
    }
    return;
  }
  if (blockIdx.z == 2) {
    int base = ((blockIdx.y * 98 + blockIdx.x) * 256 + threadIdx.x) * 2;
#pragma unroll
    for (int e = base; e < base + 2; ++e) {
      if (e < 768 * 256) wq[e] = f2bf(qkv_w[e]);
      else if (e < 768 * 256 + 256 * 256) {
        int e2 = e - 768 * 256;
        wp[e2] = f2bf(proj_w[e2]);
      }
    }
    return;
  }
  __shared__ float tile[32][33];
  const int hw0 = blockIdx.x * 32, c0 = blockIdx.y * 32, b = blockIdx.z;
  const int tx = threadIdx.x & 31, ty = threadIdx.x >> 5;
  const float* xb = x + ((size_t)b * CCH + c0) * HWT + hw0;
#pragma unroll
  for (int i = 0; i < 4; ++i) {
    int c = ty + i * 8;
    tile[c][tx] = xb[(size_t)c * HWT + tx];
  }
  __syncthreads();
  ushort* xo = xt + ((size_t)b * HWT + hw0) * CCH + c0;
#pragma unroll
  for (int i = 0; i < 4; ++i) {
    int hwl = ty + i * 8;
    xo[(size_t)hwl * CCH + tx] = f2bf(tile[tx][hwl]);
  }
}

// ---------------------------------------------------------------------------
// bf16 MFMA GEMM, (MI*32) x 128 tile, BK=32, 4 waves (2x2), 16x16x32 frags.
// MODE 0 (qkv, MI=4): epilogue -> fp16; q (bn,hw,d)*scale; v (bn,hw,d);
//   k TRANSPOSED as kT8[(bn*4+d/8)][hw][8] for 16B-per-lane QK gathers.
// MODE 1 (proj, MI=2): epilogue -> fp32 out (b,o,hw) + bias.
// ---------------------------------------------------------------------------
template <int MODE, int MI>
__global__ __launch_bounds__(256) void mfma_gemm_k(
    const ushort* __restrict__ A, int rowsA,
    const ushort* __restrict__ B, int rowsB,
    const float* __restrict__ biasv, void* __restrict__ outp) {
  __shared__ ushort Alds[MI * 32 * 32];
  __shared__ ushort Blds[128 * 32];

  const int t  = threadIdx.x;
  const int m0 = blockIdx.y * (MI * 32);
  const int n0 = blockIdx.x * 128;
  const int b  = blockIdx.z;

  const ushort* Ab = A;
  const ushort* Bb = B + (size_t)b * HWT * CCH;

  const int lane  = t & 63;
  const int wid   = t >> 6;
  const int wm    = (wid >> 1) * (MI * 16);
  const int wn    = (wid & 1) * 64;
  const int lrow  = lane & 15;
  const int cwant = lane >> 4;
  const int csw   = (cwant ^ ((lrow >> 1) & 3)) * 8;

  const int srow   = t >> 2;
  const int scslot = t & 3;
  const int wlds   = wid << 9;

  f32x4 acc[MI][4];
#pragma unroll
  for (int i = 0; i < MI; ++i)
#pragma unroll
    for (int j = 0; j < 4; ++j) acc[i][j] = (f32x4){0.f, 0.f, 0.f, 0.f};

  for (int k0 = 0; k0 < CCH; k0 += 32) {
    __syncthreads();
#pragma unroll
    for (int h = 0; h < MI / 2; ++h) {   // A halves
      const int lr   = srow + h * 64;
      const int csrc = (scslot ^ ((lr >> 1) & 3)) * 8;
      int ga = m0 + lr; ga = ga < rowsA ? ga : rowsA - 1;
      const ushort* gpa = Ab + (size_t)ga * CCH + k0 + csrc;
      ushort* lpa = Alds + h * 2048 + wlds;
      __builtin_amdgcn_global_load_lds(
          (const __attribute__((address_space(1))) void*)gpa,
          (__attribute__((address_space(3))) void*)lpa, 16, 0, 0);
    }
#pragma unroll
    for (int h = 0; h < 2; ++h) {        // B halves
      const int lr   = srow + h * 64;
      const int csrc = (scslot ^ ((lr >> 1) & 3)) * 8;
      int gb = n0 + lr; gb = gb < rowsB ? gb : rowsB - 1;
      const ushort* gpb = Bb + (size_t)gb * CCH + k0 + csrc;
      ushort* lpb = Blds + h * 2048 + wlds;
      __builtin_amdgcn_global_load_lds(
          (const __attribute__((address_space(1))) void*)gpb,
          (__attribute__((address_space(3))) void*)lpb, 16, 0, 0);
    }
    __syncthreads();

    short8 af[MI], bf[4];
#pragma unroll
    for (int mi = 0; mi < MI; ++mi)
      af[mi] = *(const short8*)&Alds[(wm + mi * 16 + lrow) * 32 + csw];
#pragma unroll
    for (int ni = 0; ni < 4; ++ni)
      bf[ni] = *(const short8*)&Blds[(wn + ni * 16 + lrow) * 32 + csw];
#pragma unroll
    for (int mi = 0; mi < MI; ++mi)
#pragma unroll
      for (int ni = 0; ni < 4; ++ni)
        acc[mi][ni] = __builtin_amdgcn_mfma_f32_16x16x32_bf16(
            af[mi], bf[ni], acc[mi][ni], 0, 0, 0);
  }

  const int row4 = (lane >> 4) * 4;
  if (MODE == 0) {
    _Float16* qh = (_Float16*)outp;
#pragma unroll
    for (int mi = 0; mi < MI; ++mi) {
      const int o0 = m0 + wm + mi * 16 + row4;   // quad of consecutive o
      const int t3 = o0 >> 8, c0 = o0 & 255;
      const int head = c0 >> 5, d0 = c0 & 31;
      const float sc = (t3 == 0) ? SCALE : 1.f;
      float bv[4];
#pragma unroll
      for (int r = 0; r < 4; ++r) bv[r] = biasv[o0 + r];
      if (t3 == 1) {
        // kT8: ((bn*4 + d0/8) * HWT + hw) * 8 + (d0&7)
        _Float16* base = qh + (size_t)QKV_ELEMS +
                         ((size_t)(b * NH + head) * 4 + (d0 >> 3)) * (HWT * 8) +
                         (d0 & 7);
#pragma unroll
        for (int ni = 0; ni < 4; ++ni) {
          const int hw = n0 + wn + ni * 16 + lrow;
          if (hw < HWT) {
            half4v pack;
#pragma unroll
            for (int r = 0; r < 4; ++r)
              pack[r] = (_Float16)(acc[mi][ni][r] + bv[r]);
            *(half4v*)(base + (size_t)hw * 8) = pack;
          }
        }
      } else {
        _Float16* base = qh + (size_t)t3 * QKV_ELEMS +
                         (size_t)(b * NH + head) * HWT * 32 + d0;
#pragma unroll
        for (int ni = 0; ni < 4; ++ni) {
          const int hw = n0 + wn + ni * 16 + lrow;
          if (hw < HWT) {
            half4v pack;
#pragma unroll
            for (int r = 0; r < 4; ++r)
              pack[r] = (_Float16)((acc[mi][ni][r] + bv[r]) * sc);
            *(half4v*)(base + (size_t)hw * 32) = pack;
          }
        }
      }
    }
  } else {
    float* op = (float*)outp;
#pragma unroll
    for (int mi = 0; mi < MI; ++mi)
#pragma unroll
      for (int r = 0; r < 4; ++r) {
        const int o = m0 + wm + mi * 16 + row4 + r;
        const float bvv = biasv[o];
#pragma unroll
        for (int ni = 0; ni < 4; ++ni) {
          const int hw = n0 + wn + ni * 16 + lrow;
          if (hw < HWT)
            op[((size_t)b * CCH + o) * HWT + hw] = acc[mi][ni][r] + bvv;
        }
      }
  }
}

// ---------------------------------------------------------------------------
// attn_v5: v4 skeleton, tuned for latency hiding + VALU cut.
// Block = 16 px (128 thr, 2 waves), grid 3136 (XCD-swizzled),
// __launch_bounds__(128,5) -> 20 waves/CU, 10 blocks/CU resident.
// Phase A: per wave 8 px; ALL 8 src16 loads hoisted; K in 4 batches of 2 px
//   (8 x 16B in flight); Q via readfirstlane (scalar path); 16 fdot2/px;
//   packed score (s<<16 | f16(a)) -> LDS row (wid*8 + pp).
// Phase B: thread = (px, oc=4ch); 7 groups of 7 j: 7 LDS reads + 7 V loads,
//   then 7x2 v_pk_fma_f16 (a replicated to half2); chunk-flush to f32.
// ---------------------------------------------------------------------------
__global__ __launch_bounds__(128, 5) void attn_v5_k(
    const _Float16* __restrict__ q_h, const _Float16* __restrict__ kt8,
    const _Float16* __restrict__ v_h, const float* __restrict__ relbias,
    const ushort* __restrict__ src16, ushort* __restrict__ att_t) {
  // bijective XCD swizzle (3136 % 8 == 0): each XCD owns 2 bn slices
  const int id  = blockIdx.x;
  const int idx = (id & 7) * 392 + (id >> 3);
  const int bn  = idx / 196;
  const int g   = idx % 196;
  const int px0 = g * 16;
  const int b = bn >> 3, n = bn & 7;

  __shared__ float bias_s[169];
  __shared__ uint32_t as_lds[16 * 49];

  const int tid = threadIdx.x;
  for (int i = tid; i < 169; i += 128) bias_s[i] = relbias[i * NH + n];
  __syncthreads();

  const int wid = tid >> 6, lane = tid & 63;
  const int jc = lane < 49 ? lane : 48;
  const int jbias = (jc / 7) * 13 + jc % 7;   // per-lane constant

  const _Float16* kb = kt8 + (size_t)bn * 4 * HWT * 8;
  const _Float16* vb = v_h + (size_t)bn * HWT * 32;
  const _Float16* qb = q_h + (size_t)bn * HWT * 32;

  const int pxw = px0 + wid * 8;

  // ---- hoisted: src16 + bias index for all 8 px of this wave ----
  int sv[8], bb[8];
#pragma unroll
  for (int p = 0; p < 8; ++p) {
    const int px = pxw + p;
    const int h = px / WIMG, w = px % WIMG;
    int ph = h - 3; ph = ph < 0 ? 0 : (ph > 49 ? 49 : ph);
    int pw = w - 3; pw = pw < 0 ? 0 : (pw > 49 ? 49 : pw);
    const int l = ph * 50 + pw;
    const int bih = (h < 3) ? h : ((h < 53) ? 3 : h - 49);
    const int biw = (w < 3) ? w : ((w < 53) ? 3 : w - 49);
    bb[p] = bih * 13 + biw + jbias;
    sv[p] = (int)src16[l * 49 + jc];             // coalesced 98B run
  }

  // ---- Phase A: 4 batches of 2 px ----
#pragma unroll
  for (int batch = 0; batch < 4; ++batch) {
    union V16 { uint4 u; half2v h2[4]; };
    V16 K[2][4];
#pragma unroll
    for (int p = 0; p < 2; ++p)
#pragma unroll
      for (int dq = 0; dq < 4; ++dq)
        K[p][dq].u =
            *(const uint4*)(kb + ((size_t)dq * HWT + sv[batch * 2 + p]) * 8);

#pragma unroll
    for (int p = 0; p < 2; ++p) {
      const int pp = batch * 2 + p;
      const int pxu = __builtin_amdgcn_readfirstlane(pxw + pp);
      union V64 { uint4 u[4]; half2v hv[16]; };
      V64 Q;                                      // uniform -> scalar loads
      const uint4* qp = (const uint4*)(qb + (size_t)pxu * 32);
#pragma unroll
      for (int i = 0; i < 4; ++i) Q.u[i] = qp[i];
      const float bvv = bias_s[bb[pp]];

      float a0 = 0.f, a1 = 0.f, a2 = 0.f, a3 = 0.f;
#if HAVE_FDOT2
#pragma unroll
      for (int i = 0; i < 4; ++i) {
        a0 = __builtin_amdgcn_fdot2(K[p][0].h2[i], Q.hv[i],      a0, false);
        a1 = __builtin_amdgcn_fdot2(K[p][1].h2[i], Q.hv[4 + i],  a1, false);
        a2 = __builtin_amdgcn_fdot2(K[p][2].h2[i], Q.hv[8 + i],  a2, false);
        a3 = __builtin_amdgcn_fdot2(K[p][3].h2[i], Q.hv[12 + i], a3, false);
      }
#else
#pragma unroll
      for (int i = 0; i < 4; ++i) {
        a0 += (float)K[p][0].h2[i][0] * (float)Q.hv[i][0] +
              (float)K[p][0].h2[i][1] * (float)Q.hv[i][1];
        a1 += (float)K[p][1].h2[i][0] * (float)Q.hv[4 + i][0] +
              (float)K[p][1].h2[i][1] * (float)Q.hv[4 + i][1];
        a2 += (float)K[p][2].h2[i][0] * (float)Q.hv[8 + i][0] +
              (float)K[p][2].h2[i][1] * (float)Q.hv[8 + i][1];
        a3 += (float)K[p][3].h2[i][0] * (float)Q.hv[12 + i][0] +
              (float)K[p][3].h2[i][1] * (float)Q.hv[12 + i][1];
      }
#endif
      const float a = (a0 + a1) + (a2 + a3) + bvv;
      union { _Float16 hh; uint16_t us; } cv;
      cv.hh = (_Float16)a;
      if (lane < 49)
        as_lds[(wid * 8 + pp) * 49 + lane] = ((uint32_t)sv[pp] << 16) | cv.us;
    }
  }
  __syncthreads();

  // ---- Phase B: thread = (px, oc=4ch); 7 groups of 7 j ----
  const int pxb = tid >> 3, oc = tid & 7;
  const uint32_t* arow = &as_lds[pxb * 49];
  const _Float16* vbase = vb + oc * 4;

  float cf0 = 0.f, cf1 = 0.f, cf2 = 0.f, cf3 = 0.f;
#pragma unroll
  for (int gq = 0; gq < 7; ++gq) {
    uint32_t u[7];
#pragma unroll
    for (int i = 0; i < 7; ++i) u[i] = arow[gq * 7 + i];
    half4v vv[7];
#pragma unroll
    for (int i = 0; i < 7; ++i)
      vv[i] = *(const half4v*)(vbase + (size_t)(u[i] >> 16) * 32);

    half2v acc0 = (half2v){(_Float16)0.f, (_Float16)0.f};
    half2v acc1 = (half2v){(_Float16)0.f, (_Float16)0.f};
#pragma unroll
    for (int i = 0; i < 7; ++i) {
      union { uint32_t w; half2v h; } au;
      au.w = (u[i] << 16) | (u[i] & 0xffffu);    // a replicated to both halves
      const half2v vlo = (half2v){vv[i][0], vv[i][1]};
      const half2v vhi = (half2v){vv[i][2], vv[i][3]};
      acc0 += au.h * vlo;                         // v_pk_fma_f16
      acc1 += au.h * vhi;
    }
    cf0 += (float)acc0[0]; cf1 += (float)acc0[1];
    cf2 += (float)acc1[0]; cf3 += (float)acc1[1];
  }

  ushort tmp[4];
  tmp[0] = f2bf(cf0); tmp[1] = f2bf(cf1);
  tmp[2] = f2bf(cf2); tmp[3] = f2bf(cf3);
  *(short4v*)(att_t + ((size_t)b * HWT + px0 + pxb) * CCH + n * 32 + oc * 4) =
      *(const short4v*)tmp;
}

// ---------------------------------------------------------------------------
extern "C" void kernel_launch(void* const* d_in, const int* in_sizes, int n_in,
                              void* d_out, int out_size, void* d_ws, size_t ws_size,
                              hipStream_t stream) {
  const float* x       = (const float*)d_in[0];
  const float* qkv_w   = (const float*)d_in[1];
  const float* qkv_b   = (const float*)d_in[2];
  const float* proj_w  = (const float*)d_in[3];
  const float* proj_b  = (const float*)d_in[4];
  const float* relbias = (const float*)d_in[5];
  float* out = (float*)d_out;

  char* wsb = (char*)d_ws;
  _Float16* qh  = (_Float16*)wsb;                      // q fp16 (bn,hw,d)
  _Float16* kt8 = qh + (size_t)QKV_ELEMS;              // kT fp16 (bn,d/8,hw,8)
  _Float16* vh  = qh + (size_t)2 * QKV_ELEMS;          // v fp16 (bn,hw,d)
  ushort*   xt  = (ushort*)(wsb + (size_t)3 * QKV_ELEMS * 2); // bf16 (b,hw,c)
  ushort*   wq  = xt + (size_t)QKV_ELEMS;              // bf16 768x256
  ushort*   wp  = wq + 768 * 256;                      // bf16 256x256
  ushort*   src16 = wp + 256 * 256;                    // u16, 2500*49
  ushort*   att_t = xt;  // alias: xt fully consumed by qkv GEMM first

  hipLaunchKernelGGL(prep_k, dim3(98, 8, 4), dim3(256), 0, stream,
                     x, qkv_w, proj_w, xt, wq, wp, src16);
  // qkv: A=wq (m=o, 768 rows), B=xt (n=hw) -> fp16 q/kT8/v
  hipLaunchKernelGGL((mfma_gemm_k<0, 4>), dim3(25, 6, 2), dim3(256), 0, stream,
                     wq, 768, xt, HWT, qkv_b, (void*)qh);
  hipLaunchKernelGGL(attn_v5_k, dim3(3136), dim3(128), 0, stream,
                     qh, kt8, vh, relbias, src16, att_t);
  // proj: A=wp (m=o, 256 rows, BM=64), B=att_t (n=hw) -> fp32 out
  hipLaunchKernelGGL((mfma_gemm_k<1, 2>), dim3(25, 4, 2), dim3(256), 0, stream,
                     wp, 256, att_t, HWT, proj_b, (void*)out);
}

// Round 12
// 52.523 us; speedup vs baseline: 3.5723x; 1.0334x over previous
//
#include <hip/hip_runtime.h>
#include <cstddef>
#include <cstdint>

#define HWT   3136        // 56*56
#define WIMG  56
#define CCH   256
#define NH    8
#define QKV_ELEMS (16 * HWT * 32)   // per-tensor q/k/v elements
#define SCALE 0.17677669529663687f  // 32^-0.5

typedef __attribute__((ext_vector_type(8))) short short8;
typedef __attribute__((ext_vector_type(4))) short short4v;
typedef __attribute__((ext_vector_type(4))) float f32x4;
typedef _Float16 half2v __attribute__((ext_vector_type(2)));
typedef _Float16 half4v __attribute__((ext_vector_type(4)));
typedef _Float16 half8v __attribute__((ext_vector_type(8)));

#if defined(__has_builtin)
#if __has_builtin(__builtin_amdgcn_fdot2)
#define HAVE_FDOT2 1
#endif
#endif
#ifndef HAVE_FDOT2
#define HAVE_FDOT2 0
#endif

__device__ __forceinline__ ushort f2bf(float f) {
  union { float f; uint32_t u; } v; v.f = f;
  uint32_t u = v.u;
  u += 0x7fffu + ((u >> 16) & 1u);   // round-to-nearest-even
  return (ushort)(u >> 16);
}

// ---------------------------------------------------------------------------
// prep: z<2  -> transpose x (b,c,hw) f32 -> xt (b,hw,c) bf16
//       z==2 -> convert qkv_w / proj_w to bf16
//       z==3 -> build src16 table (reshape-reinterpret semantics)
// ---------------------------------------------------------------------------
__global__ __launch_bounds__(256) void prep_k(
    const float* __restrict__ x, const float* __restrict__ qkv_w,
    const float* __restrict__ proj_w, ushort* __restrict__ xt,
    ushort* __restrict__ wq, ushort* __restrict__ wp,
    ushort* __restrict__ src16) {
  if (blockIdx.z == 3) {
    int e = (blockIdx.y * 98 + blockIdx.x) * 256 + threadIdx.x;
    if (e < 2500 * 49) {
      int sp = e / 2500;
      int pos = e - sp * 2500;
      int i = pos / 50 + sp / 7;
      int j = pos % 50 + sp % 7;
      src16[e] = (ushort)(i * WIMG + j);
    }
    return;
  }
  if (blockIdx.z == 2) {
    int base = ((blockIdx.y * 98 + blockIdx.x) * 256 + threadIdx.x) * 2;
#pragma unroll
    for (int e = base; e < base + 2; ++e) {
      if (e < 768 * 256) wq[e] = f2bf(qkv_w[e]);
      else if (e < 768 * 256 + 256 * 256) {
        int e2 = e - 768 * 256;
        wp[e2] = f2bf(proj_w[e2]);
      }
    }
    return;
  }
  __shared__ float tile[32][33];
  const int hw0 = blockIdx.x * 32, c0 = blockIdx.y * 32, b = blockIdx.z;
  const int tx = threadIdx.x & 31, ty = threadIdx.x >> 5;
  const float* xb = x + ((size_t)b * CCH + c0) * HWT + hw0;
#pragma unroll
  for (int i = 0; i < 4; ++i) {
    int c = ty + i * 8;
    tile[c][tx] = xb[(size_t)c * HWT + tx];
  }
  __syncthreads();
  ushort* xo = xt + ((size_t)b * HWT + hw0) * CCH + c0;
#pragma unroll
  for (int i = 0; i < 4; ++i) {
    int hwl = ty + i * 8;
    xo[(size_t)hwl * CCH + tx] = f2bf(tile[tx][hwl]);
  }
}

// ---------------------------------------------------------------------------
// bf16 MFMA GEMM, (MI*32) x 128 tile, BK=32, 4 waves (2x2), 16x16x32 frags.
// MODE 0 (qkv, MI=4): epilogue -> fp16; q (bn,hw,d)*scale; v (bn,hw,d);
//   k TRANSPOSED as kT8[(bn*4+d/8)][hw][8] for 16B-per-lane QK gathers.
// MODE 1 (proj, MI=2): epilogue -> fp32 out (b,o,hw) + bias.
// ---------------------------------------------------------------------------
template <int MODE, int MI>
__global__ __launch_bounds__(256) void mfma_gemm_k(
    const ushort* __restrict__ A, int rowsA,
    const ushort* __restrict__ B, int rowsB,
    const float* __restrict__ biasv, void* __restrict__ outp) {
  __shared__ ushort Alds[MI * 32 * 32];
  __shared__ ushort Blds[128 * 32];

  const int t  = threadIdx.x;
  const int m0 = blockIdx.y * (MI * 32);
  const int n0 = blockIdx.x * 128;
  const int b  = blockIdx.z;

  const ushort* Ab = A;
  const ushort* Bb = B + (size_t)b * HWT * CCH;

  const int lane  = t & 63;
  const int wid   = t >> 6;
  const int wm    = (wid >> 1) * (MI * 16);
  const int wn    = (wid & 1) * 64;
  const int lrow  = lane & 15;
  const int cwant = lane >> 4;
  const int csw   = (cwant ^ ((lrow >> 1) & 3)) * 8;

  const int srow   = t >> 2;
  const int scslot = t & 3;
  const int wlds   = wid << 9;

  f32x4 acc[MI][4];
#pragma unroll
  for (int i = 0; i < MI; ++i)
#pragma unroll
    for (int j = 0; j < 4; ++j) acc[i][j] = (f32x4){0.f, 0.f, 0.f, 0.f};

  for (int k0 = 0; k0 < CCH; k0 += 32) {
    __syncthreads();
#pragma unroll
    for (int h = 0; h < MI / 2; ++h) {   // A halves
      const int lr   = srow + h * 64;
      const int csrc = (scslot ^ ((lr >> 1) & 3)) * 8;
      int ga = m0 + lr; ga = ga < rowsA ? ga : rowsA - 1;
      const ushort* gpa = Ab + (size_t)ga * CCH + k0 + csrc;
      ushort* lpa = Alds + h * 2048 + wlds;
      __builtin_amdgcn_global_load_lds(
          (const __attribute__((address_space(1))) void*)gpa,
          (__attribute__((address_space(3))) void*)lpa, 16, 0, 0);
    }
#pragma unroll
    for (int h = 0; h < 2; ++h) {        // B halves
      const int lr   = srow + h * 64;
      const int csrc = (scslot ^ ((lr >> 1) & 3)) * 8;
      int gb = n0 + lr; gb = gb < rowsB ? gb : rowsB - 1;
      const ushort* gpb = Bb + (size_t)gb * CCH + k0 + csrc;
      ushort* lpb = Blds + h * 2048 + wlds;
      __builtin_amdgcn_global_load_lds(
          (const __attribute__((address_space(1))) void*)gpb,
          (__attribute__((address_space(3))) void*)lpb, 16, 0, 0);
    }
    __syncthreads();

    short8 af[MI], bf[4];
#pragma unroll
    for (int mi = 0; mi < MI; ++mi)
      af[mi] = *(const short8*)&Alds[(wm + mi * 16 + lrow) * 32 + csw];
#pragma unroll
    for (int ni = 0; ni < 4; ++ni)
      bf[ni] = *(const short8*)&Blds[(wn + ni * 16 + lrow) * 32 + csw];
#pragma unroll
    for (int mi = 0; mi < MI; ++mi)
#pragma unroll
      for (int ni = 0; ni < 4; ++ni)
        acc[mi][ni] = __builtin_amdgcn_mfma_f32_16x16x32_bf16(
            af[mi], bf[ni], acc[mi][ni], 0, 0, 0);
  }

  const int row4 = (lane >> 4) * 4;
  if (MODE == 0) {
    _Float16* qh = (_Float16*)outp;
#pragma unroll
    for (int mi = 0; mi < MI; ++mi) {
      const int o0 = m0 + wm + mi * 16 + row4;   // quad of consecutive o
      const int t3 = o0 >> 8, c0 = o0 & 255;
      const int head = c0 >> 5, d0 = c0 & 31;
      const float sc = (t3 == 0) ? SCALE : 1.f;
      float bv[4];
#pragma unroll
      for (int r = 0; r < 4; ++r) bv[r] = biasv[o0 + r];
      if (t3 == 1) {
        // kT8: ((bn*4 + d0/8) * HWT + hw) * 8 + (d0&7)
        _Float16* base = qh + (size_t)QKV_ELEMS +
                         ((size_t)(b * NH + head) * 4 + (d0 >> 3)) * (HWT * 8) +
                         (d0 & 7);
#pragma unroll
        for (int ni = 0; ni < 4; ++ni) {
          const int hw = n0 + wn + ni * 16 + lrow;
          if (hw < HWT) {
            half4v pack;
#pragma unroll
            for (int r = 0; r < 4; ++r)
              pack[r] = (_Float16)(acc[mi][ni][r] + bv[r]);
            *(half4v*)(base + (size_t)hw * 8) = pack;
          }
        }
      } else {
        _Float16* base = qh + (size_t)t3 * QKV_ELEMS +
                         (size_t)(b * NH + head) * HWT * 32 + d0;
#pragma unroll
        for (int ni = 0; ni < 4; ++ni) {
          const int hw = n0 + wn + ni * 16 + lrow;
          if (hw < HWT) {
            half4v pack;
#pragma unroll
            for (int r = 0; r < 4; ++r)
              pack[r] = (_Float16)((acc[mi][ni][r] + bv[r]) * sc);
            *(half4v*)(base + (size_t)hw * 32) = pack;
          }
        }
      }
    }
  } else {
    float* op = (float*)outp;
#pragma unroll
    for (int mi = 0; mi < MI; ++mi)
#pragma unroll
      for (int r = 0; r < 4; ++r) {
        const int o = m0 + wm + mi * 16 + row4 + r;
        const float bvv = biasv[o];
#pragma unroll
        for (int ni = 0; ni < 4; ++ni) {
          const int hw = n0 + wn + ni * 16 + lrow;
          if (hw < HWT)
            op[((size_t)b * CCH + o) * HWT + hw] = acc[mi][ni][r] + bvv;
        }
      }
  }
}

// ---------------------------------------------------------------------------
// attn_v6: phase A identical to v5 (passing). Phase B restructured to halve
// V-side TA requests: lane = (px in [0,16), oc4 in [0,4)) reads 16B of V per
// instr -> ONE instr covers 16 px per j (was 2 at 8B). j-range split across
// the 2 waves (w0: j<25, w1: j>=25), partials merged via LDS. f32 accum via
// fma_mix; bf16 store 16B/lane (1 instr per 4 px).
// ---------------------------------------------------------------------------
__global__ __launch_bounds__(128, 5) void attn_v6_k(
    const _Float16* __restrict__ q_h, const _Float16* __restrict__ kt8,
    const _Float16* __restrict__ v_h, const float* __restrict__ relbias,
    const ushort* __restrict__ src16, ushort* __restrict__ att_t) {
  // bijective XCD swizzle (3136 % 8 == 0): each XCD owns 2 bn slices
  const int id  = blockIdx.x;
  const int idx = (id & 7) * 392 + (id >> 3);
  const int bn  = idx / 196;
  const int g   = idx % 196;
  const int px0 = g * 16;
  const int b = bn >> 3, n = bn & 7;

  __shared__ float bias_s[169];
  __shared__ uint32_t as_lds[16 * 49];
  __shared__ float part_lds[64][8];

  const int tid = threadIdx.x;
  for (int i = tid; i < 169; i += 128) bias_s[i] = relbias[i * NH + n];
  __syncthreads();

  const int wid = tid >> 6, lane = tid & 63;
  const int jc = lane < 49 ? lane : 48;
  const int jbias = (jc / 7) * 13 + jc % 7;   // per-lane constant

  const _Float16* kb = kt8 + (size_t)bn * 4 * HWT * 8;
  const _Float16* vb = v_h + (size_t)bn * HWT * 32;
  const _Float16* qb = q_h + (size_t)bn * HWT * 32;

  const int pxw = px0 + wid * 8;

  // ---- hoisted: src16 + bias index for all 8 px of this wave ----
  int sv[8], bb[8];
#pragma unroll
  for (int p = 0; p < 8; ++p) {
    const int px = pxw + p;
    const int h = px / WIMG, w = px % WIMG;
    int ph = h - 3; ph = ph < 0 ? 0 : (ph > 49 ? 49 : ph);
    int pw = w - 3; pw = pw < 0 ? 0 : (pw > 49 ? 49 : pw);
    const int l = ph * 50 + pw;
    const int bih = (h < 3) ? h : ((h < 53) ? 3 : h - 49);
    const int biw = (w < 3) ? w : ((w < 53) ? 3 : w - 49);
    bb[p] = bih * 13 + biw + jbias;
    sv[p] = (int)src16[l * 49 + jc];             // coalesced 98B run
  }

  // ---- Phase A: 4 batches of 2 px ----
#pragma unroll
  for (int batch = 0; batch < 4; ++batch) {
    union V16 { uint4 u; half2v h2[4]; };
    V16 K[2][4];
#pragma unroll
    for (int p = 0; p < 2; ++p)
#pragma unroll
      for (int dq = 0; dq < 4; ++dq)
        K[p][dq].u =
            *(const uint4*)(kb + ((size_t)dq * HWT + sv[batch * 2 + p]) * 8);

#pragma unroll
    for (int p = 0; p < 2; ++p) {
      const int pp = batch * 2 + p;
      const int pxu = __builtin_amdgcn_readfirstlane(pxw + pp);
      union V64 { uint4 u[4]; half2v hv[16]; };
      V64 Q;                                      // uniform -> scalar loads
      const uint4* qp = (const uint4*)(qb + (size_t)pxu * 32);
#pragma unroll
      for (int i = 0; i < 4; ++i) Q.u[i] = qp[i];
      const float bvv = bias_s[bb[pp]];

      float a0 = 0.f, a1 = 0.f, a2 = 0.f, a3 = 0.f;
#if HAVE_FDOT2
#pragma unroll
      for (int i = 0; i < 4; ++i) {
        a0 = __builtin_amdgcn_fdot2(K[p][0].h2[i], Q.hv[i],      a0, false);
        a1 = __builtin_amdgcn_fdot2(K[p][1].h2[i], Q.hv[4 + i],  a1, false);
        a2 = __builtin_amdgcn_fdot2(K[p][2].h2[i], Q.hv[8 + i],  a2, false);
        a3 = __builtin_amdgcn_fdot2(K[p][3].h2[i], Q.hv[12 + i], a3, false);
      }
#else
#pragma unroll
      for (int i = 0; i < 4; ++i) {
        a0 += (float)K[p][0].h2[i][0] * (float)Q.hv[i][0] +
              (float)K[p][0].h2[i][1] * (float)Q.hv[i][1];
        a1 += (float)K[p][1].h2[i][0] * (float)Q.hv[4 + i][0] +
              (float)K[p][1].h2[i][1] * (float)Q.hv[4 + i][1];
        a2 += (float)K[p][2].h2[i][0] * (float)Q.hv[8 + i][0] +
              (float)K[p][2].h2[i][1] * (float)Q.hv[8 + i][1];
        a3 += (float)K[p][3].h2[i][0] * (float)Q.hv[12 + i][0] +
              (float)K[p][3].h2[i][1] * (float)Q.hv[12 + i][1];
      }
#endif
      const float a = (a0 + a1) + (a2 + a3) + bvv;
      union { _Float16 hh; uint16_t us; } cv;
      cv.hh = (_Float16)a;
      if (lane < 49)
        as_lds[(wid * 8 + pp) * 49 + lane] = ((uint32_t)sv[pp] << 16) | cv.us;
    }
  }
  __syncthreads();

  // ---- Phase B: lane = (px in [0,16), oc4 in [0,4)); j split across waves.
  const int pxb = lane >> 2, oc4 = lane & 3;
  const _Float16* vbase = vb + oc4 * 8;     // 16B = 8 channels per lane
  const uint32_t* arow = &as_lds[pxb * 49];
  const int jbase = wid * 25;               // w0: j 0..24, w1: j 25..48
  const int jcnt  = wid ? 24 : 25;

  float acc[8];
#pragma unroll
  for (int c = 0; c < 8; ++c) acc[c] = 0.f;

#pragma unroll
  for (int jj = 0; jj < 25; ++jj) {
    if (jj < jcnt) {
      const uint32_t u = arow[jbase + jj];   // 4 lanes same addr: broadcast
      union { uint16_t us; _Float16 hh; } cv;
      cv.us = (uint16_t)(u & 0xffffu);
      const float a = (float)cv.hh;
      const int s = (int)(u >> 16);
      const half8v vv = *(const half8v*)(vbase + (size_t)s * 32);
#pragma unroll
      for (int c = 0; c < 8; ++c) acc[c] += a * (float)vv[c];  // fma_mix
    }
  }

  if (wid == 1) {
#pragma unroll
    for (int c = 0; c < 8; ++c) part_lds[lane][c] = acc[c];
  }
  __syncthreads();
  if (wid == 0) {
#pragma unroll
    for (int c = 0; c < 8; ++c) acc[c] += part_lds[lane][c];
    ushort tmp[8];
#pragma unroll
    for (int c = 0; c < 8; ++c) tmp[c] = f2bf(acc[c]);
    *(short8*)(att_t + ((size_t)b * HWT + px0 + pxb) * CCH + n * 32 + oc4 * 8) =
        *(const short8*)tmp;
  }
}

// ---------------------------------------------------------------------------
extern "C" void kernel_launch(void* const* d_in, const int* in_sizes, int n_in,
                              void* d_out, int out_size, void* d_ws, size_t ws_size,
                              hipStream_t stream) {
  const float* x       = (const float*)d_in[0];
  const float* qkv_w   = (const float*)d_in[1];
  const float* qkv_b   = (const float*)d_in[2];
  const float* proj_w  = (const float*)d_in[3];
  const float* proj_b  = (const float*)d_in[4];
  const float* relbias = (const float*)d_in[5];
  float* out = (float*)d_out;

  char* wsb = (char*)d_ws;
  _Float16* qh  = (_Float16*)wsb;                      // q fp16 (bn,hw,d)
  _Float16* kt8 = qh + (size_t)QKV_ELEMS;              // kT fp16 (bn,d/8,hw,8)
  _Float16* vh  = qh + (size_t)2 * QKV_ELEMS;          // v fp16 (bn,hw,d)
  ushort*   xt  = (ushort*)(wsb + (size_t)3 * QKV_ELEMS * 2); // bf16 (b,hw,c)
  ushort*   wq  = xt + (size_t)QKV_ELEMS;              // bf16 768x256
  ushort*   wp  = wq + 768 * 256;                      // bf16 256x256
  ushort*   src16 = wp + 256 * 256;                    // u16, 2500*49
  ushort*   att_t = xt;  // alias: xt fully consumed by qkv GEMM first

  hipLaunchKernelGGL(prep_k, dim3(98, 8, 4), dim3(256), 0, stream,
                     x, qkv_w, proj_w, xt, wq, wp, src16);
  // qkv: A=wq (m=o, 768 rows), B=xt (n=hw) -> fp16 q/kT8/v
  hipLaunchKernelGGL((mfma_gemm_k<0, 4>), dim3(25, 6, 2), dim3(256), 0, stream,
                     wq, 768, xt, HWT, qkv_b, (void*)qh);
  hipLaunchKernelGGL(attn_v6_k, dim3(3136), dim3(128), 0, stream,
                     qh, kt8, vh, relbias, src16, att_t);
  // proj: A=wp (m=o, 256 rows, BM=64), B=att_t (n=hw) -> fp32 out
  hipLaunchKernelGGL((mfma_gemm_k<1, 2>), dim3(25, 4, 2), dim3(256), 0, stream,
                     wp, 256, att_t, HWT, proj_b, (void*)out);
}

// Round 13
// 49.450 us; speedup vs baseline: 3.7943x; 1.0621x over previous
//
#include <hip/hip_runtime.h>
#include <cstddef>
#include <cstdint>

#define HWT   3136        // 56*56
#define WIMG  56
#define CCH   256
#define NH    8
#define QKV_ELEMS (16 * HWT * 32)   // per-tensor q/k/v elements
#define SCALE 0.17677669529663687f  // 32^-0.5

typedef __attribute__((ext_vector_type(8))) short short8;
typedef __attribute__((ext_vector_type(4))) short short4v;
typedef __attribute__((ext_vector_type(4))) float f32x4;
typedef _Float16 half2v __attribute__((ext_vector_type(2)));
typedef _Float16 half4v __attribute__((ext_vector_type(4)));
typedef _Float16 half8v __attribute__((ext_vector_type(8)));

#if defined(__has_builtin)
#if __has_builtin(__builtin_amdgcn_fdot2)
#define HAVE_FDOT2 1
#endif
#endif
#ifndef HAVE_FDOT2
#define HAVE_FDOT2 0
#endif

__device__ __forceinline__ ushort f2bf(float f) {
  union { float f; uint32_t u; } v; v.f = f;
  uint32_t u = v.u;
  u += 0x7fffu + ((u >> 16) & 1u);   // round-to-nearest-even
  return (ushort)(u >> 16);
}

// ---------------------------------------------------------------------------
// prep: z<2  -> transpose x (b,c,hw) f32 -> xt (b,hw,c) bf16
//       z==2 -> convert qkv_w / proj_w to bf16
//       z==3 -> build src16 table (reshape-reinterpret semantics)
// ---------------------------------------------------------------------------
__global__ __launch_bounds__(256) void prep_k(
    const float* __restrict__ x, const float* __restrict__ qkv_w,
    const float* __restrict__ proj_w, ushort* __restrict__ xt,
    ushort* __restrict__ wq, ushort* __restrict__ wp,
    ushort* __restrict__ src16) {
  if (blockIdx.z == 3) {
    int e = (blockIdx.y * 98 + blockIdx.x) * 256 + threadIdx.x;
    if (e < 2500 * 49) {
      int sp = e / 2500;
      int pos = e - sp * 2500;
      int i = pos / 50 + sp / 7;
      int j = pos % 50 + sp % 7;
      src16[e] = (ushort)(i * WIMG + j);
    }
    return;
  }
  if (blockIdx.z == 2) {
    int base = ((blockIdx.y * 98 + blockIdx.x) * 256 + threadIdx.x) * 2;
#pragma unroll
    for (int e = base; e < base + 2; ++e) {
      if (e < 768 * 256) wq[e] = f2bf(qkv_w[e]);
      else if (e < 768 * 256 + 256 * 256) {
        int e2 = e - 768 * 256;
        wp[e2] = f2bf(proj_w[e2]);
      }
    }
    return;
  }
  __shared__ float tile[32][33];
  const int hw0 = blockIdx.x * 32, c0 = blockIdx.y * 32, b = blockIdx.z;
  const int tx = threadIdx.x & 31, ty = threadIdx.x >> 5;
  const float* xb = x + ((size_t)b * CCH + c0) * HWT + hw0;
#pragma unroll
  for (int i = 0; i < 4; ++i) {
    int c = ty + i * 8;
    tile[c][tx] = xb[(size_t)c * HWT + tx];
  }
  __syncthreads();
  ushort* xo = xt + ((size_t)b * HWT + hw0) * CCH + c0;
#pragma unroll
  for (int i = 0; i < 4; ++i) {
    int hwl = ty + i * 8;
    xo[(size_t)hwl * CCH + tx] = f2bf(tile[tx][hwl]);
  }
}

// ---------------------------------------------------------------------------
// bf16 MFMA GEMM, (MI*32) x 64 tile, BK=32, 4 waves (2x2), 16x16x32 frags.
// BN=64 / smaller BM vs earlier rounds: 2-4x block count so co-resident
// blocks overlap the per-block staging-barrier latency (GEMMs were
// occupancy/latency-bound at 300/200 blocks).
// MODE 0 (qkv, MI=2, grid y=12): epilogue -> fp16 q*scale / kT8 / v.
// MODE 1 (proj, MI=1, grid y=8): epilogue -> fp32 out (b,o,hw) + bias.
// ---------------------------------------------------------------------------
template <int MODE, int MI>
__global__ __launch_bounds__(256) void mfma_gemm_k(
    const ushort* __restrict__ A, int rowsA,
    const ushort* __restrict__ B, int rowsB,
    const float* __restrict__ biasv, void* __restrict__ outp) {
  __shared__ ushort Alds[MI * 32 * 32];
  __shared__ ushort Blds[64 * 32];

  const int t  = threadIdx.x;
  const int m0 = blockIdx.y * (MI * 32);
  const int n0 = blockIdx.x * 64;
  const int b  = blockIdx.z;

  const ushort* Ab = A;
  const ushort* Bb = B + (size_t)b * HWT * CCH;

  const int lane  = t & 63;
  const int wid   = t >> 6;
  const int wm    = (wid >> 1) * (MI * 16);
  const int wn    = (wid & 1) * 32;
  const int lrow  = lane & 15;
  const int cwant = lane >> 4;
  const int csw   = (cwant ^ ((lrow >> 1) & 3)) * 8;

  const int srow   = t >> 2;        // staging row (4 thr x 16B per row)
  const int scslot = t & 3;
  const int wlds   = wid << 9;      // wave's 1KB LDS staging window (elems)

  f32x4 acc[MI][2];
#pragma unroll
  for (int i = 0; i < MI; ++i)
#pragma unroll
    for (int j = 0; j < 2; ++j) acc[i][j] = (f32x4){0.f, 0.f, 0.f, 0.f};

  for (int k0 = 0; k0 < CCH; k0 += 32) {
    __syncthreads();
    // A staging: MI*32 rows
#pragma unroll
    for (int h = 0; h < (MI + 1) / 2; ++h) {
      const int lr = srow + h * 64;
      if (lr < MI * 32) {
        const int csrc = (scslot ^ ((lr >> 1) & 3)) * 8;
        int ga = m0 + lr; ga = ga < rowsA ? ga : rowsA - 1;
        const ushort* gpa = Ab + (size_t)ga * CCH + k0 + csrc;
        ushort* lpa = Alds + h * 2048 + wlds;
        __builtin_amdgcn_global_load_lds(
            (const __attribute__((address_space(1))) void*)gpa,
            (__attribute__((address_space(3))) void*)lpa, 16, 0, 0);
      }
    }
    // B staging: 64 rows (exactly one round, all 256 threads)
    {
      const int lr = srow;
      const int csrc = (scslot ^ ((lr >> 1) & 3)) * 8;
      int gb = n0 + lr; gb = gb < rowsB ? gb : rowsB - 1;
      const ushort* gpb = Bb + (size_t)gb * CCH + k0 + csrc;
      ushort* lpb = Blds + wlds;
      __builtin_amdgcn_global_load_lds(
          (const __attribute__((address_space(1))) void*)gpb,
          (__attribute__((address_space(3))) void*)lpb, 16, 0, 0);
    }
    __syncthreads();

    short8 af[MI], bf[2];
#pragma unroll
    for (int mi = 0; mi < MI; ++mi)
      af[mi] = *(const short8*)&Alds[(wm + mi * 16 + lrow) * 32 + csw];
#pragma unroll
    for (int ni = 0; ni < 2; ++ni)
      bf[ni] = *(const short8*)&Blds[(wn + ni * 16 + lrow) * 32 + csw];
#pragma unroll
    for (int mi = 0; mi < MI; ++mi)
#pragma unroll
      for (int ni = 0; ni < 2; ++ni)
        acc[mi][ni] = __builtin_amdgcn_mfma_f32_16x16x32_bf16(
            af[mi], bf[ni], acc[mi][ni], 0, 0, 0);
  }

  const int row4 = (lane >> 4) * 4;
  if (MODE == 0) {
    _Float16* qh = (_Float16*)outp;
#pragma unroll
    for (int mi = 0; mi < MI; ++mi) {
      const int o0 = m0 + wm + mi * 16 + row4;   // quad of consecutive o
      const int t3 = o0 >> 8, c0 = o0 & 255;
      const int head = c0 >> 5, d0 = c0 & 31;
      const float sc = (t3 == 0) ? SCALE : 1.f;
      float bv[4];
#pragma unroll
      for (int r = 0; r < 4; ++r) bv[r] = biasv[o0 + r];
      if (t3 == 1) {
        // kT8: ((bn*4 + d0/8) * HWT + hw) * 8 + (d0&7)
        _Float16* base = qh + (size_t)QKV_ELEMS +
                         ((size_t)(b * NH + head) * 4 + (d0 >> 3)) * (HWT * 8) +
                         (d0 & 7);
#pragma unroll
        for (int ni = 0; ni < 2; ++ni) {
          const int hw = n0 + wn + ni * 16 + lrow;
          if (hw < HWT) {
            half4v pack;
#pragma unroll
            for (int r = 0; r < 4; ++r)
              pack[r] = (_Float16)(acc[mi][ni][r] + bv[r]);
            *(half4v*)(base + (size_t)hw * 8) = pack;
          }
        }
      } else {
        _Float16* base = qh + (size_t)t3 * QKV_ELEMS +
                         (size_t)(b * NH + head) * HWT * 32 + d0;
#pragma unroll
        for (int ni = 0; ni < 2; ++ni) {
          const int hw = n0 + wn + ni * 16 + lrow;
          if (hw < HWT) {
            half4v pack;
#pragma unroll
            for (int r = 0; r < 4; ++r)
              pack[r] = (_Float16)((acc[mi][ni][r] + bv[r]) * sc);
            *(half4v*)(base + (size_t)hw * 32) = pack;
          }
        }
      }
    }
  } else {
    float* op = (float*)outp;
#pragma unroll
    for (int mi = 0; mi < MI; ++mi)
#pragma unroll
      for (int r = 0; r < 4; ++r) {
        const int o = m0 + wm + mi * 16 + row4 + r;
        const float bvv = biasv[o];
#pragma unroll
        for (int ni = 0; ni < 2; ++ni) {
          const int hw = n0 + wn + ni * 16 + lrow;
          if (hw < HWT)
            op[((size_t)b * CCH + o) * HWT + hw] = acc[mi][ni][r] + bvv;
        }
      }
  }
}

// ---------------------------------------------------------------------------
// attn_v6 (unchanged from R12, passing): phase A = v5; phase B 16B/lane V
// reads, j-range split across 2 waves, LDS partial merge.
// ---------------------------------------------------------------------------
__global__ __launch_bounds__(128, 5) void attn_v6_k(
    const _Float16* __restrict__ q_h, const _Float16* __restrict__ kt8,
    const _Float16* __restrict__ v_h, const float* __restrict__ relbias,
    const ushort* __restrict__ src16, ushort* __restrict__ att_t) {
  // bijective XCD swizzle (3136 % 8 == 0): each XCD owns 2 bn slices
  const int id  = blockIdx.x;
  const int idx = (id & 7) * 392 + (id >> 3);
  const int bn  = idx / 196;
  const int g   = idx % 196;
  const int px0 = g * 16;
  const int b = bn >> 3, n = bn & 7;

  __shared__ float bias_s[169];
  __shared__ uint32_t as_lds[16 * 49];
  __shared__ float part_lds[64][8];

  const int tid = threadIdx.x;
  for (int i = tid; i < 169; i += 128) bias_s[i] = relbias[i * NH + n];
  __syncthreads();

  const int wid = tid >> 6, lane = tid & 63;
  const int jc = lane < 49 ? lane : 48;
  const int jbias = (jc / 7) * 13 + jc % 7;   // per-lane constant

  const _Float16* kb = kt8 + (size_t)bn * 4 * HWT * 8;
  const _Float16* vb = v_h + (size_t)bn * HWT * 32;
  const _Float16* qb = q_h + (size_t)bn * HWT * 32;

  const int pxw = px0 + wid * 8;

  // ---- hoisted: src16 + bias index for all 8 px of this wave ----
  int sv[8], bb[8];
#pragma unroll
  for (int p = 0; p < 8; ++p) {
    const int px = pxw + p;
    const int h = px / WIMG, w = px % WIMG;
    int ph = h - 3; ph = ph < 0 ? 0 : (ph > 49 ? 49 : ph);
    int pw = w - 3; pw = pw < 0 ? 0 : (pw > 49 ? 49 : pw);
    const int l = ph * 50 + pw;
    const int bih = (h < 3) ? h : ((h < 53) ? 3 : h - 49);
    const int biw = (w < 3) ? w : ((w < 53) ? 3 : w - 49);
    bb[p] = bih * 13 + biw + jbias;
    sv[p] = (int)src16[l * 49 + jc];             // coalesced 98B run
  }

  // ---- Phase A: 4 batches of 2 px ----
#pragma unroll
  for (int batch = 0; batch < 4; ++batch) {
    union V16 { uint4 u; half2v h2[4]; };
    V16 K[2][4];
#pragma unroll
    for (int p = 0; p < 2; ++p)
#pragma unroll
      for (int dq = 0; dq < 4; ++dq)
        K[p][dq].u =
            *(const uint4*)(kb + ((size_t)dq * HWT + sv[batch * 2 + p]) * 8);

#pragma unroll
    for (int p = 0; p < 2; ++p) {
      const int pp = batch * 2 + p;
      const int pxu = __builtin_amdgcn_readfirstlane(pxw + pp);
      union V64 { uint4 u[4]; half2v hv[16]; };
      V64 Q;                                      // uniform -> scalar loads
      const uint4* qp = (const uint4*)(qb + (size_t)pxu * 32);
#pragma unroll
      for (int i = 0; i < 4; ++i) Q.u[i] = qp[i];
      const float bvv = bias_s[bb[pp]];

      float a0 = 0.f, a1 = 0.f, a2 = 0.f, a3 = 0.f;
#if HAVE_FDOT2
#pragma unroll
      for (int i = 0; i < 4; ++i) {
        a0 = __builtin_amdgcn_fdot2(K[p][0].h2[i], Q.hv[i],      a0, false);
        a1 = __builtin_amdgcn_fdot2(K[p][1].h2[i], Q.hv[4 + i],  a1, false);
        a2 = __builtin_amdgcn_fdot2(K[p][2].h2[i], Q.hv[8 + i],  a2, false);
        a3 = __builtin_amdgcn_fdot2(K[p][3].h2[i], Q.hv[12 + i], a3, false);
      }
#else
#pragma unroll
      for (int i = 0; i < 4; ++i) {
        a0 += (float)K[p][0].h2[i][0] * (float)Q.hv[i][0] +
              (float)K[p][0].h2[i][1] * (float)Q.hv[i][1];
        a1 += (float)K[p][1].h2[i][0] * (float)Q.hv[4 + i][0] +
              (float)K[p][1].h2[i][1] * (float)Q.hv[4 + i][1];
        a2 += (float)K[p][2].h2[i][0] * (float)Q.hv[8 + i][0] +
              (float)K[p][2].h2[i][1] * (float)Q.hv[8 + i][1];
        a3 += (float)K[p][3].h2[i][0] * (float)Q.hv[12 + i][0] +
              (float)K[p][3].h2[i][1] * (float)Q.hv[12 + i][1];
      }
#endif
      const float a = (a0 + a1) + (a2 + a3) + bvv;
      union { _Float16 hh; uint16_t us; } cv;
      cv.hh = (_Float16)a;
      if (lane < 49)
        as_lds[(wid * 8 + pp) * 49 + lane] = ((uint32_t)sv[pp] << 16) | cv.us;
    }
  }
  __syncthreads();

  // ---- Phase B: lane = (px in [0,16), oc4 in [0,4)); j split across waves.
  const int pxb = lane >> 2, oc4 = lane & 3;
  const _Float16* vbase = vb + oc4 * 8;     // 16B = 8 channels per lane
  const uint32_t* arow = &as_lds[pxb * 49];
  const int jbase = wid * 25;               // w0: j 0..24, w1: j 25..48
  const int jcnt  = wid ? 24 : 25;

  float acc[8];
#pragma unroll
  for (int c = 0; c < 8; ++c) acc[c] = 0.f;

#pragma unroll
  for (int jj = 0; jj < 25; ++jj) {
    if (jj < jcnt) {
      const uint32_t u = arow[jbase + jj];   // 4 lanes same addr: broadcast
      union { uint16_t us; _Float16 hh; } cv;
      cv.us = (uint16_t)(u & 0xffffu);
      const float a = (float)cv.hh;
      const int s = (int)(u >> 16);
      const half8v vv = *(const half8v*)(vbase + (size_t)s * 32);
#pragma unroll
      for (int c = 0; c < 8; ++c) acc[c] += a * (float)vv[c];  // fma_mix
    }
  }

  if (wid == 1) {
#pragma unroll
    for (int c = 0; c < 8; ++c) part_lds[lane][c] = acc[c];
  }
  __syncthreads();
  if (wid == 0) {
#pragma unroll
    for (int c = 0; c < 8; ++c) acc[c] += part_lds[lane][c];
    ushort tmp[8];
#pragma unroll
    for (int c = 0; c < 8; ++c) tmp[c] = f2bf(acc[c]);
    *(short8*)(att_t + ((size_t)b * HWT + px0 + pxb) * CCH + n * 32 + oc4 * 8) =
        *(const short8*)tmp;
  }
}

// ---------------------------------------------------------------------------
extern "C" void kernel_launch(void* const* d_in, const int* in_sizes, int n_in,
                              void* d_out, int out_size, void* d_ws, size_t ws_size,
                              hipStream_t stream) {
  const float* x       = (const float*)d_in[0];
  const float* qkv_w   = (const float*)d_in[1];
  const float* qkv_b   = (const float*)d_in[2];
  const float* proj_w  = (const float*)d_in[3];
  const float* proj_b  = (const float*)d_in[4];
  const float* relbias = (const float*)d_in[5];
  float* out = (float*)d_out;

  char* wsb = (char*)d_ws;
  _Float16* qh  = (_Float16*)wsb;                      // q fp16 (bn,hw,d)
  _Float16* kt8 = qh + (size_t)QKV_ELEMS;              // kT fp16 (bn,d/8,hw,8)
  _Float16* vh  = qh + (size_t)2 * QKV_ELEMS;          // v fp16 (bn,hw,d)
  ushort*   xt  = (ushort*)(wsb + (size_t)3 * QKV_ELEMS * 2); // bf16 (b,hw,c)
  ushort*   wq  = xt + (size_t)QKV_ELEMS;              // bf16 768x256
  ushort*   wp  = wq + 768 * 256;                      // bf16 256x256
  ushort*   src16 = wp + 256 * 256;                    // u16, 2500*49
  ushort*   att_t = xt;  // alias: xt fully consumed by qkv GEMM first

  hipLaunchKernelGGL(prep_k, dim3(98, 8, 4), dim3(256), 0, stream,
                     x, qkv_w, proj_w, xt, wq, wp, src16);
  // qkv: A=wq (m=o, 768 rows, MI=2 -> BM=64), B=xt (n=hw, BN=64)
  hipLaunchKernelGGL((mfma_gemm_k<0, 2>), dim3(49, 12, 2), dim3(256), 0, stream,
                     wq, 768, xt, HWT, qkv_b, (void*)qh);
  hipLaunchKernelGGL(attn_v6_k, dim3(3136), dim3(128), 0, stream,
                     qh, kt8, vh, relbias, src16, att_t);
  // proj: A=wp (m=o, 256 rows, MI=1 -> BM=32), B=att_t (n=hw, BN=64)
  hipLaunchKernelGGL((mfma_gemm_k<1, 1>), dim3(49, 8, 2), dim3(256), 0, stream,
                     wp, 256, att_t, HWT, proj_b, (void*)out);
}